// Round 6
// baseline (1590.006 us; speedup 1.0000x reference)
//
#include <hip/hip_runtime.h>
#include <math.h>

#define NROWS 1024
#define DCOLS 16384
#define NTOT  16777216
#define BINS  1000

typedef short short8 __attribute__((ext_vector_type(8)));
typedef unsigned short ushort8 __attribute__((ext_vector_type(8)));
typedef float f32x4 __attribute__((ext_vector_type(4)));

#define GLOAD_LDS16(gp, lp) __builtin_amdgcn_global_load_lds( \
    (const __attribute__((address_space(1))) unsigned int*)(gp), \
    (__attribute__((address_space(3))) unsigned int*)(lp), 16, 0, 0)

// ---------------- K0: split x into bf16 hi/lo planes (RNE, deterministic) ----------------
__global__ __launch_bounds__(256) void k_split(const float* __restrict__ x,
    unsigned short* __restrict__ phi, unsigned short* __restrict__ plo) {
  const size_t i = ((size_t)blockIdx.x * 256 + threadIdx.x) * 8;
  const float4 v0 = *(const float4*)(x + i);
  const float4 v1 = *(const float4*)(x + i + 4);
  const float vv[8] = {v0.x, v0.y, v0.z, v0.w, v1.x, v1.y, v1.z, v1.w};
  ushort8 h, lo;
  #pragma unroll
  for (int c = 0; c < 8; ++c) {
    unsigned ub = __float_as_uint(vv[c]);
    unsigned hb = (ub + 0x7FFFu + ((ub >> 16) & 1u)) >> 16;       // RNE bf16
    float hf = __uint_as_float(hb << 16);
    float r = vv[c] - hf;                                          // exact
    unsigned ur = __float_as_uint(r);
    unsigned lb = (ur + 0x7FFFu + ((ur >> 16) & 1u)) >> 16;       // RNE bf16
    h[c]  = (unsigned short)hb;
    lo[c] = (unsigned short)lb;
  }
  *(ushort8*)(phi + i) = h;
  *(ushort8*)(plo + i) = lo;
}

// ---------------- K1: per-row sum / sumsq / min / max (fp64 accumulation) ----------------
__global__ __launch_bounds__(256) void k_rowstats(const float* __restrict__ x,
    double* __restrict__ rowsum, double* __restrict__ rowsumsq,
    double* __restrict__ rowmin, double* __restrict__ rowmax) {
  const int row = blockIdx.x;
  const int t = threadIdx.x;
  const float4* xr = (const float4*)(x + (size_t)row * DCOLS);
  double s = 0.0, s2 = 0.0;
  float mn = 3.4028235e38f, mx = -3.4028235e38f;
  for (int j = t; j < DCOLS / 4; j += 256) {
    float4 v = xr[j];
    double a = v.x, b = v.y, c = v.z, d = v.w;
    s  += (a + b) + (c + d);
    s2 += (a * a + b * b) + (c * c + d * d);
    mn = fminf(mn, fminf(fminf(v.x, v.y), fminf(v.z, v.w)));
    mx = fmaxf(mx, fmaxf(fmaxf(v.x, v.y), fmaxf(v.z, v.w)));
  }
  #pragma unroll
  for (int off = 32; off > 0; off >>= 1) {
    s  += __shfl_down(s, off);
    s2 += __shfl_down(s2, off);
    mn = fminf(mn, __shfl_down(mn, off));
    mx = fmaxf(mx, __shfl_down(mx, off));
  }
  __shared__ double lsd[8];
  __shared__ float  lsf[8];
  const int lane = t & 63, w = t >> 6;
  if (lane == 0) { lsd[w] = s; lsd[4 + w] = s2; lsf[w] = mn; lsf[4 + w] = mx; }
  __syncthreads();
  if (t == 0) {
    rowsum[row]   = (lsd[0] + lsd[1]) + (lsd[2] + lsd[3]);
    rowsumsq[row] = (lsd[4] + lsd[5]) + (lsd[6] + lsd[7]);
    rowmin[row] = (double)fminf(fminf(lsf[0], lsf[1]), fminf(lsf[2], lsf[3]));
    rowmax[row] = (double)fmaxf(fmaxf(lsf[4], lsf[5]), fmaxf(lsf[6], lsf[7]));
  }
}

// ---------------- K2: global scalars (fp64 stats -> float32 np-style scalars) ----------------
__global__ __launch_bounds__(256) void k_stats2(
    const double* __restrict__ rowsum, const double* __restrict__ rowsumsq,
    const double* __restrict__ rowmin, const double* __restrict__ rowmax,
    double* __restrict__ m, double* __restrict__ dn, float* __restrict__ fscal,
    float* __restrict__ flg) {
#pragma clang fp contract(off)
  const int t = threadIdx.x;
  double s = 0.0, s2 = 0.0, mn = 1e300, mx = -1e300;
  for (int r = t; r < NROWS; r += 256) {
    s += rowsum[r]; s2 += rowsumsq[r];
    mn = fmin(mn, rowmin[r]); mx = fmax(mx, rowmax[r]);
  }
  #pragma unroll
  for (int off = 32; off > 0; off >>= 1) {
    s  += __shfl_down(s, off);
    s2 += __shfl_down(s2, off);
    mn = fmin(mn, __shfl_down(mn, off));
    mx = fmax(mx, __shfl_down(mx, off));
  }
  __shared__ double lsd[16];
  const int lane = t & 63, w = t >> 6;
  if (lane == 0) { lsd[w] = s; lsd[4 + w] = s2; lsd[8 + w] = mn; lsd[12 + w] = mx; }
  __syncthreads();
  if (t == 0) {
    double S  = (lsd[0] + lsd[1]) + (lsd[2] + lsd[3]);
    double S2 = (lsd[4] + lsd[5]) + (lsd[6] + lsd[7]);
    double MN = fmin(fmin(lsd[8], lsd[9]), fmin(lsd[10], lsd[11]));
    double MX = fmax(fmax(lsd[12], lsd[13]), fmax(lsd[14], lsd[15]));
    const double N = 16777216.0;
    double mu  = S / N;
    double var = (S2 - S * S / N) / (N - 1.0);
    double sig = sqrt(var);
    float mu32 = (float)mu;
    float sg32 = (float)sig;
    float mnf  = (float)MN;
    float mxf  = (float)MX;
    float lof  = (mnf - mu32) / sg32;
    float hif  = (mxf - mu32) / sg32;
    float wf   = (hif - lof) / 1000.0f;
    fscal[0] = mu32;
    fscal[1] = sg32;
    fscal[2] = lof;
    fscal[3] = wf;
    fscal[4] = 16384.0f * wf;
    fscal[5] = 16777216.0f * wf;
    flg[0] = 0.0f;
  }
  __syncthreads();
  for (int r = t; r < NROWS; r += 256) {
    double rs = rowsum[r];
    m[r]  = rs / 16384.0;
    dn[r] = sqrt(rowsumsq[r] - rs * rs * (1.0 / 16384.0));
  }
}

// ---- K5a: MFMA Gram, 64x32 tile, FULL K per block; grid = 16 row-tiles x 32 col-tiles ----
__global__ __launch_bounds__(256) void k_gramm(
    const unsigned short* __restrict__ phi, const unsigned short* __restrict__ plo,
    const double* __restrict__ m, const double* __restrict__ dn,
    double* __restrict__ fpart, float* __restrict__ dbg) {
  __shared__ short As[2][64][32];   // [plane][row][k]
  __shared__ short Bs[2][32][32];
  const int t = threadIdx.x;
  const int w = t >> 6, l = t & 63;
  const int b = blockIdx.x;
  const int bj = b & 31, bi = b >> 5;          // bi in 0..15 (512 blocks!)

  // staging roles: w0 A-hi (4 instr), w1 A-lo (4), w2 B-hi (2), w3 B-lo (2)
  const unsigned short* plane = (w & 1) ? plo : phi;
  const bool isB = (w >= 2);
  const int prow0 = isB ? bj * 32 : bi * 64;
  short* lbase = isB ? &Bs[w & 1][0][0] : &As[w & 1][0][0];
  const int nq = isB ? 2 : 4;
  const unsigned short* gbase = plane + (size_t)(prow0 + (l >> 2)) * DCOLS + (l & 3) * 8;

  f32x4 acc[2] = {{0.f,0.f,0.f,0.f},{0.f,0.f,0.f,0.f}};
  double dacc[2][4] = {{0,0,0,0},{0,0,0,0}};
  const int arow = w * 16 + (l & 15);
  const int koff = (l >> 4) * 8;

  for (int K0 = 0; K0 < DCOLS; K0 += 512) {
    for (int k0 = K0; k0 < K0 + 512; k0 += 32) {
      __syncthreads();                    // previous chunk fully consumed
      for (int q = 0; q < nq; ++q)
        GLOAD_LDS16(gbase + (size_t)q * 16 * DCOLS + k0, lbase + q * 512);
      __syncthreads();                    // staging drained
      short8 ah = *(const short8*)&As[0][arow][koff];
      short8 al = *(const short8*)&As[1][arow][koff];
      #pragma unroll
      for (int cj = 0; cj < 2; ++cj) {
        short8 bh = *(const short8*)&Bs[0][cj * 16 + (l & 15)][koff];
        short8 bl = *(const short8*)&Bs[1][cj * 16 + (l & 15)][koff];
        acc[cj] = __builtin_amdgcn_mfma_f32_16x16x32_bf16(ah, bh, acc[cj], 0, 0, 0);
        acc[cj] = __builtin_amdgcn_mfma_f32_16x16x32_bf16(ah, bl, acc[cj], 0, 0, 0);
        acc[cj] = __builtin_amdgcn_mfma_f32_16x16x32_bf16(al, bh, acc[cj], 0, 0, 0);
      }
    }
    #pragma unroll
    for (int cj = 0; cj < 2; ++cj) {
      #pragma unroll
      for (int v = 0; v < 4; ++v) dacc[cj][v] += (double)acc[cj][v];
      acc[cj] = (f32x4){0.f, 0.f, 0.f, 0.f};
    }
  }

  // debug dump: block b=1 (bi=0, cols 32..63), wave 0 rows 0..15
  if (b == 1 && w == 0) {
    #pragma unroll
    for (int cj = 0; cj < 2; ++cj)
      #pragma unroll
      for (int v = 0; v < 4; ++v)
        dbg[((l >> 4) * 4 + v) * 32 + cj * 16 + (l & 15)] = (float)dacc[cj][v];
  }

  // epilogue: C/D layout col=lane&15, row=(lane>>4)*4+v
  const int row0 = bi * 64 + w * 16 + (l >> 4) * 4;
  double mc[2], idc[2];
  #pragma unroll
  for (int cj = 0; cj < 2; ++cj) {
    int c = bj * 32 + cj * 16 + (l & 15);
    mc[cj] = m[c];
    idc[cj] = 1.0 / dn[c];
  }
  #pragma unroll
  for (int v = 0; v < 4; ++v) {
    double mi = m[row0 + v] * 16384.0;
    double s = 0.0;
    #pragma unroll
    for (int cj = 0; cj < 2; ++cj)
      s += fabs(dacc[cj][v] - mi * mc[cj]) * idc[cj];
    s += __shfl_xor(s, 1); s += __shfl_xor(s, 2);
    s += __shfl_xor(s, 4); s += __shfl_xor(s, 8);
    if ((l & 15) == 0)
      fpart[(size_t)(row0 + v) * 32 + bj] = s;
  }
}

// ---- K5c: self-check — exact fp64 Gram strip (rows 0..15 x cols 32..63, full K) ----
__global__ __launch_bounds__(256) void k_check(const float* __restrict__ x,
    const double* __restrict__ m, const double* __restrict__ dn,
    const double* __restrict__ fpart, const float* __restrict__ dbg,
    float* __restrict__ flg) {
  const int t = threadIdx.x;
  const int r = t >> 4;             // 0..15
  const int c0 = (t & 15) * 2;      // 0..30
  double g[2] = {0.0, 0.0};
  const float4* xr = (const float4*)(x + (size_t)r * DCOLS);
  const float4* xa = (const float4*)(x + (size_t)(32 + c0) * DCOLS);
  const float4* xb = (const float4*)(x + (size_t)(33 + c0) * DCOLS);
  for (int k = 0; k < DCOLS / 4; ++k) {
    float4 vr = xr[k], va = xa[k], vb = xb[k];
    g[0] += (double)vr.x * va.x + (double)vr.y * va.y
          + (double)vr.z * va.z + (double)vr.w * va.w;
    g[1] += (double)vr.x * vb.x + (double)vr.y * vb.y
          + (double)vr.z * vb.z + (double)vr.w * vb.w;
  }
  double mH[4] = {0, 0, 0, 0};
  double partial = 0.0;
  #pragma unroll
  for (int q = 0; q < 2; ++q) {
    int cc = c0 + q;
    int cj16 = cc & 16, bb = cc & 15;
    double G = g[q];
    double den = fmax(fabs(G), 64.0);
    int pr = ((r & 3) << 2) | (r >> 2);
    int pb = ((bb & 3) << 2) | (bb >> 2);
    mH[0] = fmax(mH[0], fabs((double)dbg[r  * 32 + cc      ] - G) / den);
    mH[1] = fmax(mH[1], fabs((double)dbg[bb * 32 + cj16 + r] - G) / den);
    mH[2] = fmax(mH[2], fabs((double)dbg[pr * 32 + cc      ] - G) / den);
    mH[3] = fmax(mH[3], fabs((double)dbg[pb * 32 + cj16 + r] - G) / den);
    partial += fabs(G - 16384.0 * m[r] * m[32 + cc]) / dn[32 + cc];
  }
  partial += __shfl_xor(partial, 1); partial += __shfl_xor(partial, 2);
  partial += __shfl_xor(partial, 4); partial += __shfl_xor(partial, 8);
  __shared__ double rs_[16];
  if ((t & 15) == 0) rs_[r] = partial;
  #pragma unroll
  for (int off = 1; off < 64; off <<= 1) {
    #pragma unroll
    for (int i = 0; i < 4; ++i) mH[i] = fmax(mH[i], __shfl_xor(mH[i], off));
  }
  __shared__ double hw[4][4];
  if ((t & 63) == 0) {
    #pragma unroll
    for (int i = 0; i < 4; ++i) hw[t >> 6][i] = mH[i];
  }
  __syncthreads();
  if (t == 0) {
    double H[4];
    #pragma unroll
    for (int i = 0; i < 4; ++i)
      H[i] = fmax(fmax(hw[0][i], hw[1][i]), fmax(hw[2][i], hw[3][i]));
    double fperr = 0.0;
    for (int rr = 0; rr < 16; ++rr) {
      double exact = rs_[rr];
      double got = fpart[(size_t)rr * 32 + 1];
      fperr = fmax(fperr, fabs(got - exact) / fmax(fabs(exact), 1e-30));
    }
    float code = 0.0f;
    // threshold 2e-3: bf16-split+f32-MFMA noise is <=2e-5 rel (100x margin);
    // any layout/indexing bug is O(1) rel.
    if (H[0] > 2e-3 || fperr > 2e-3) {
      int best = 0; double bv = H[0];
      for (int i = 1; i < 4; ++i) if (H[i] < bv) { bv = H[i]; best = i; }
      if (bv > 2e-3) best = 8;
      double mag = -log10(fmax(H[0], 1e-12));
      mag = fmin(fmax(mag, 0.0), 99.0);
      code = 1e6f * (float)(1 + best) + 1e4f * (float)floor(mag)
           + ((fperr > 2e-3) ? 5e5f : 0.0f);
    }
    flg[0] = code;
  }
}

// ---------------- K5b: fallback fp32-VALU Gram (small ws) ----------------
__global__ __launch_bounds__(256) void k_gram(const float* __restrict__ x,
    const double* __restrict__ m, const double* __restrict__ dn,
    double* __restrict__ fpart) {
  __shared__ float As[32][72];
  __shared__ float Bs[32][72];
  __shared__ double red[64][16];
  const int t = threadIdx.x;
  const int bi = blockIdx.y, bj = blockIdx.x;
  const int tx = t & 15, ty = t >> 4;
  const int lr = t >> 2, lc = t & 3;
  const float* Ap = x + (size_t)(bi * 64 + lr) * DCOLS;
  const float* Bp = x + (size_t)(bj * 64 + lr) * DCOLS;
  double acc[4][4];
  #pragma unroll
  for (int i = 0; i < 4; ++i)
    #pragma unroll
    for (int j = 0; j < 4; ++j) acc[i][j] = 0.0;
  float4 a0 = ((const float4*)Ap)[lc];
  float4 a1 = ((const float4*)Ap)[lc + 4];
  float4 b0 = ((const float4*)Bp)[lc];
  float4 b1 = ((const float4*)Bp)[lc + 4];
  for (int k0 = 0; k0 < DCOLS; k0 += 32) {
    __syncthreads();
    {
      const float* a0p = (const float*)&a0;
      const float* a1p = (const float*)&a1;
      const float* b0p = (const float*)&b0;
      const float* b1p = (const float*)&b1;
      #pragma unroll
      for (int jj = 0; jj < 4; ++jj) {
        As[lc * 4 + jj][lr]      = a0p[jj];
        As[16 + lc * 4 + jj][lr] = a1p[jj];
        Bs[lc * 4 + jj][lr]      = b0p[jj];
        Bs[16 + lc * 4 + jj][lr] = b1p[jj];
      }
    }
    __syncthreads();
    if (k0 + 32 < DCOLS) {
      a0 = ((const float4*)(Ap + k0 + 32))[lc];
      a1 = ((const float4*)(Ap + k0 + 32))[lc + 4];
      b0 = ((const float4*)(Bp + k0 + 32))[lc];
      b1 = ((const float4*)(Bp + k0 + 32))[lc + 4];
    }
    float ac[4][4];
    #pragma unroll
    for (int i = 0; i < 4; ++i)
      #pragma unroll
      for (int j = 0; j < 4; ++j) ac[i][j] = 0.0f;
    #pragma unroll
    for (int k = 0; k < 32; ++k) {
      const float4 av = *(const float4*)&As[k][ty * 4];
      const float4 bv = *(const float4*)&Bs[k][tx * 4];
      const float aa[4] = {av.x, av.y, av.z, av.w};
      const float bb[4] = {bv.x, bv.y, bv.z, bv.w};
      #pragma unroll
      for (int i = 0; i < 4; ++i)
        #pragma unroll
        for (int j = 0; j < 4; ++j)
          ac[i][j] += aa[i] * bb[j];
    }
    #pragma unroll
    for (int i = 0; i < 4; ++i)
      #pragma unroll
      for (int j = 0; j < 4; ++j) acc[i][j] += (double)ac[i][j];
  }
  double mr[4], mc[4], dc[4];
  #pragma unroll
  for (int i = 0; i < 4; ++i) mr[i] = m[bi * 64 + ty * 4 + i];
  #pragma unroll
  for (int j = 0; j < 4; ++j) {
    int col = bj * 64 + tx * 4 + j;
    mc[j] = m[col]; dc[j] = dn[col];
  }
  #pragma unroll
  for (int i = 0; i < 4; ++i) {
    double pi = 0.0;
    #pragma unroll
    for (int j = 0; j < 4; ++j) {
      double cov = acc[i][j] - 16384.0 * mr[i] * mc[j];
      pi += fabs(cov) / dc[j];
    }
    red[ty * 4 + i][tx] = pi;
  }
  __syncthreads();
  if (t < 64) {
    double ssum = 0.0;
    #pragma unroll
    for (int q = 0; q < 16; ++q) ssum += red[t][q];
    fpart[(size_t)(bi * 64 + t) * 16 + bj] = ssum;
  }
}

// ---------------- K3: per-row histogram (float32 np binning) + local entropy ----------------
__global__ __launch_bounds__(256) void k_hist(const float* __restrict__ x,
    const float* __restrict__ fscal, double* __restrict__ localent,
    unsigned* __restrict__ bc) {
#pragma clang fp contract(off)
  __shared__ unsigned h[BINS];
  const int row = blockIdx.x, t = threadIdx.x;
  for (int b = t; b < BINS; b += 256) h[b] = 0;
  __syncthreads();
  const float mu32 = fscal[0], sg32 = fscal[1], lof = fscal[2], wf = fscal[3];
  const float4* xr = (const float4*)(x + (size_t)row * DCOLS);
  for (int j = t; j < DCOLS / 4; j += 256) {
    float4 v = xr[j];
    float vv[4] = {v.x, v.y, v.z, v.w};
    #pragma unroll
    for (int c = 0; c < 4; ++c) {
      float tn = (vv[c] - mu32) / sg32;
      float q  = (tn - lof) / wf;
      int idx = (int)floorf(q);
      idx = idx < 0 ? 0 : (idx > BINS - 1 ? BINS - 1 : idx);
      atomicAdd(&h[idx], 1u);
    }
  }
  __syncthreads();
  const double Dw = (double)fscal[4];
  double ls = 0.0;
  for (int b = t; b < BINS; b += 256) {
    unsigned c = h[b];
    if (c) {
      atomicAdd(&bc[b], c);
      double pd = (double)c / Dw;
      ls -= pd * log2(pd);
    }
  }
  #pragma unroll
  for (int off = 32; off > 0; off >>= 1) ls += __shfl_down(ls, off);
  __shared__ double lsd[4];
  const int lane = t & 63, w = t >> 6;
  if (lane == 0) lsd[w] = ls;
  __syncthreads();
  if (t == 0) localent[row] = (lsd[0] + lsd[1]) + (lsd[2] + lsd[3]);
}

// ---------------- K4: batch entropy + per-row pf / keepf (float32 np chain) ----------------
__global__ __launch_bounds__(256) void k_final(const unsigned* __restrict__ bc,
    const float* __restrict__ fscal, const double* __restrict__ localent,
    const double* __restrict__ fpart, const double* __restrict__ dn,
    float* __restrict__ pf, float* __restrict__ kf, int nq) {
#pragma clang fp contract(off)
  const int t = threadIdx.x;
  const double Nw = (double)fscal[5];
  double be = 0.0;
  for (int b = t; b < BINS; b += 256) {
    unsigned c = bc[b];
    if (c) { double pd = (double)c / Nw; be -= pd * log2(pd); }
  }
  #pragma unroll
  for (int off = 32; off > 0; off >>= 1) be += __shfl_down(be, off);
  __shared__ double lsd[4];
  __shared__ double sbent;
  const int lane = t & 63, w = t >> 6;
  if (lane == 0) lsd[w] = be;
  __syncthreads();
  if (t == 0) sbent = (lsd[0] + lsd[1]) + (lsd[2] + lsd[3]);
  __syncthreads();
  const float bef = (float)sbent;
  for (int r = t; r < NROWS; r += 256) {
    double s = 0.0;
    for (int q = 0; q < nq; ++q) s += fpart[(size_t)r * nq + q];
    float f1f = (float)(s / (dn[r] * 1024.0));
    float lef = (float)localent[r];
    float f2f = lef / bef;
    if (f2f == 0.0f) { f1f = 0.0f; f2f = 1.0f; }
    else if (f2f < 1.0f) f2f = 1.0f / f2f;
    float keepf = f1f / f2f;
    pf[r] = 1.0f - keepf;
    kf[r] = keepf;
  }
}

// ---------------- K6: elementwise masked scale (float32 compare + division) ----------------
__global__ __launch_bounds__(256) void k_apply(const float* __restrict__ x,
    const float* __restrict__ u, const float* __restrict__ pf,
    const float* __restrict__ kf, const float* __restrict__ flg,
    float* __restrict__ out) {
#pragma clang fp contract(off)
  const size_t e = ((size_t)blockIdx.x * 256 + threadIdx.x) * 4;
  const float fl = flg[0];
  if (fl != 0.0f) {           // diagnostic mode: encode check code in out[0]
    float4 o = {0.f, 0.f, 0.f, 0.f};
    if (e == 0) o.x = fl;
    *(float4*)(out + e) = o;
    return;
  }
  const int row = (int)(e >> 14);
  const float pr = pf[row], kr = kf[row];
  const float4 xv = *(const float4*)(x + e);
  const float4 uv = *(const float4*)(u + e);
  float4 o;
  o.x = (uv.x > pr) ? (xv.x / kr) : 0.0f;
  o.y = (uv.y > pr) ? (xv.y / kr) : 0.0f;
  o.z = (uv.z > pr) ? (xv.z / kr) : 0.0f;
  o.w = (uv.w > pr) ? (xv.w / kr) : 0.0f;
  *(float4*)(out + e) = o;
}

extern "C" void kernel_launch(void* const* d_in, const int* in_sizes, int n_in,
                              void* d_out, int out_size, void* d_ws, size_t ws_size,
                              hipStream_t stream) {
  const float* x = (const float*)d_in[0];
  const float* u = (const float*)d_in[1];
  float* out = (float*)d_out;

  const size_t PLANE = (size_t)NROWS * DCOLS * sizeof(unsigned short);  // 32 MB
  const size_t TAILF = 2056 + 512 + 4;          // floats after fpart
  const size_t BIGDB = 7 * 1024 + (size_t)NROWS * 32;
  const bool big = ws_size >= 2 * PLANE + BIGDB * 8 + TAILF * 4 + BINS * 4;

  char* base = (char*)d_ws;
  unsigned short* phi = (unsigned short*)base;
  unsigned short* plo = (unsigned short*)(base + PLANE);
  double* W = big ? (double*)(base + 2 * PLANE) : (double*)base;
  const size_t NQ = big ? 32 : 16;

  double* rowsum   = W;
  double* rowsumsq = W + 1024;
  double* rowmin   = W + 2048;
  double* rowmax   = W + 3072;
  double* m        = W + 4096;
  double* dn       = W + 5120;
  double* localent = W + 6144;
  double* fpart    = W + 7168;
  float*  F        = (float*)(W + 7168 + (size_t)NROWS * NQ);
  float*  pf       = F;
  float*  kf       = F + 1024;
  float*  fscal    = F + 2048;          // 8 floats
  float*  dbg      = F + 2056;          // 512 floats
  float*  flg      = F + 2568;          // 4 floats
  unsigned* bc     = (unsigned*)(F + 2572);

  hipMemsetAsync(bc, 0, BINS * sizeof(unsigned), stream);

  k_rowstats<<<NROWS, 256, 0, stream>>>(x, rowsum, rowsumsq, rowmin, rowmax);
  k_stats2<<<1, 256, 0, stream>>>(rowsum, rowsumsq, rowmin, rowmax, m, dn, fscal, flg);
  if (big) {
    k_split<<<NTOT / (256 * 8), 256, 0, stream>>>(x, phi, plo);
    k_gramm<<<512, 256, 0, stream>>>(phi, plo, m, dn, fpart, dbg);   // 16x32 tiles
    k_check<<<1, 256, 0, stream>>>(x, m, dn, fpart, dbg, flg);
  } else {
    k_gram<<<dim3(16, 16), 256, 0, stream>>>(x, m, dn, fpart);
  }
  k_hist<<<NROWS, 256, 0, stream>>>(x, fscal, localent, bc);
  k_final<<<1, 256, 0, stream>>>(bc, fscal, localent, fpart, dn, pf, kf, (int)NQ);
  k_apply<<<NTOT / (256 * 4), 256, 0, stream>>>(x, u, pf, kf, flg, out);
}

// Round 7
// 481.398 us; speedup vs baseline: 3.3029x; 3.3029x over previous
//
#include <hip/hip_runtime.h>
#include <math.h>

#define NROWS 1024
#define DCOLS 16384
#define NTOT  16777216
#define BINS  1000

typedef short short8 __attribute__((ext_vector_type(8)));
typedef unsigned short ushort8 __attribute__((ext_vector_type(8)));
typedef float f32x4 __attribute__((ext_vector_type(4)));

#define GLOAD_LDS16(gp, lp) __builtin_amdgcn_global_load_lds( \
    (const __attribute__((address_space(1))) unsigned int*)(gp), \
    (__attribute__((address_space(3))) unsigned int*)(lp), 16, 0, 0)

// ---------------- K0: split x into bf16 hi/lo planes (RNE, deterministic) ----------------
__global__ __launch_bounds__(256) void k_split(const float* __restrict__ x,
    unsigned short* __restrict__ phi, unsigned short* __restrict__ plo) {
  const size_t i = ((size_t)blockIdx.x * 256 + threadIdx.x) * 8;
  const float4 v0 = *(const float4*)(x + i);
  const float4 v1 = *(const float4*)(x + i + 4);
  const float vv[8] = {v0.x, v0.y, v0.z, v0.w, v1.x, v1.y, v1.z, v1.w};
  ushort8 h, lo;
  #pragma unroll
  for (int c = 0; c < 8; ++c) {
    unsigned ub = __float_as_uint(vv[c]);
    unsigned hb = (ub + 0x7FFFu + ((ub >> 16) & 1u)) >> 16;       // RNE bf16
    float hf = __uint_as_float(hb << 16);
    float r = vv[c] - hf;                                          // exact
    unsigned ur = __float_as_uint(r);
    unsigned lb = (ur + 0x7FFFu + ((ur >> 16) & 1u)) >> 16;       // RNE bf16
    h[c]  = (unsigned short)hb;
    lo[c] = (unsigned short)lb;
  }
  *(ushort8*)(phi + i) = h;
  *(ushort8*)(plo + i) = lo;
}

// ---------------- K1: per-row sum / sumsq / min / max (fp64 accumulation) ----------------
__global__ __launch_bounds__(256) void k_rowstats(const float* __restrict__ x,
    double* __restrict__ rowsum, double* __restrict__ rowsumsq,
    double* __restrict__ rowmin, double* __restrict__ rowmax) {
  const int row = blockIdx.x;
  const int t = threadIdx.x;
  const float4* xr = (const float4*)(x + (size_t)row * DCOLS);
  double s = 0.0, s2 = 0.0;
  float mn = 3.4028235e38f, mx = -3.4028235e38f;
  for (int j = t; j < DCOLS / 4; j += 256) {
    float4 v = xr[j];
    double a = v.x, b = v.y, c = v.z, d = v.w;
    s  += (a + b) + (c + d);
    s2 += (a * a + b * b) + (c * c + d * d);
    mn = fminf(mn, fminf(fminf(v.x, v.y), fminf(v.z, v.w)));
    mx = fmaxf(mx, fmaxf(fmaxf(v.x, v.y), fmaxf(v.z, v.w)));
  }
  #pragma unroll
  for (int off = 32; off > 0; off >>= 1) {
    s  += __shfl_down(s, off);
    s2 += __shfl_down(s2, off);
    mn = fminf(mn, __shfl_down(mn, off));
    mx = fmaxf(mx, __shfl_down(mx, off));
  }
  __shared__ double lsd[8];
  __shared__ float  lsf[8];
  const int lane = t & 63, w = t >> 6;
  if (lane == 0) { lsd[w] = s; lsd[4 + w] = s2; lsf[w] = mn; lsf[4 + w] = mx; }
  __syncthreads();
  if (t == 0) {
    rowsum[row]   = (lsd[0] + lsd[1]) + (lsd[2] + lsd[3]);
    rowsumsq[row] = (lsd[4] + lsd[5]) + (lsd[6] + lsd[7]);
    rowmin[row] = (double)fminf(fminf(lsf[0], lsf[1]), fminf(lsf[2], lsf[3]));
    rowmax[row] = (double)fmaxf(fmaxf(lsf[4], lsf[5]), fmaxf(lsf[6], lsf[7]));
  }
}

// ---------------- K2: global scalars (fp64 stats -> float32 np-style scalars) ----------------
__global__ __launch_bounds__(256) void k_stats2(
    const double* __restrict__ rowsum, const double* __restrict__ rowsumsq,
    const double* __restrict__ rowmin, const double* __restrict__ rowmax,
    double* __restrict__ m, double* __restrict__ dn, float* __restrict__ fscal,
    float* __restrict__ flg) {
#pragma clang fp contract(off)
  const int t = threadIdx.x;
  double s = 0.0, s2 = 0.0, mn = 1e300, mx = -1e300;
  for (int r = t; r < NROWS; r += 256) {
    s += rowsum[r]; s2 += rowsumsq[r];
    mn = fmin(mn, rowmin[r]); mx = fmax(mx, rowmax[r]);
  }
  #pragma unroll
  for (int off = 32; off > 0; off >>= 1) {
    s  += __shfl_down(s, off);
    s2 += __shfl_down(s2, off);
    mn = fmin(mn, __shfl_down(mn, off));
    mx = fmax(mx, __shfl_down(mx, off));
  }
  __shared__ double lsd[16];
  const int lane = t & 63, w = t >> 6;
  if (lane == 0) { lsd[w] = s; lsd[4 + w] = s2; lsd[8 + w] = mn; lsd[12 + w] = mx; }
  __syncthreads();
  if (t == 0) {
    double S  = (lsd[0] + lsd[1]) + (lsd[2] + lsd[3]);
    double S2 = (lsd[4] + lsd[5]) + (lsd[6] + lsd[7]);
    double MN = fmin(fmin(lsd[8], lsd[9]), fmin(lsd[10], lsd[11]));
    double MX = fmax(fmax(lsd[12], lsd[13]), fmax(lsd[14], lsd[15]));
    const double N = 16777216.0;
    double mu  = S / N;
    double var = (S2 - S * S / N) / (N - 1.0);
    double sig = sqrt(var);
    float mu32 = (float)mu;
    float sg32 = (float)sig;
    float mnf  = (float)MN;
    float mxf  = (float)MX;
    float lof  = (mnf - mu32) / sg32;
    float hif  = (mxf - mu32) / sg32;
    float wf   = (hif - lof) / 1000.0f;
    fscal[0] = mu32;
    fscal[1] = sg32;
    fscal[2] = lof;
    fscal[3] = wf;
    fscal[4] = 16384.0f * wf;
    fscal[5] = 16777216.0f * wf;
    flg[0] = 0.0f;
  }
  __syncthreads();
  for (int r = t; r < NROWS; r += 256) {
    double rs = rowsum[r];
    m[r]  = rs / 16384.0;
    dn[r] = sqrt(rowsumsq[r] - rs * rs * (1.0 / 16384.0));
  }
}

// ---- K5a: MFMA Gram, 64x64 tile, upper-triangle grid, BK=64, XOR-swizzled LDS ----
// fpart[row][slot] (slot = 64-col tile 0..15): block (bi,bj) bi<=bj writes
//   rows bi-tile slot bj (row-direction) and, if bi!=bj, rows bj-tile slot bi (col-direction).
__global__ __launch_bounds__(256) void k_gramm(
    const unsigned short* __restrict__ phi, const unsigned short* __restrict__ plo,
    const double* __restrict__ m, const double* __restrict__ dn,
    double* __restrict__ fpart) {
  const int bi = blockIdx.y, bj = blockIdx.x;
  if (bj < bi) return;                       // upper triangle only
  const bool diag = (bi == bj);
  __shared__ short As[2][64][64];            // [plane][row][k] bf16, 128B rows, part-swizzled
  __shared__ short Bs[2][64][64];
  __shared__ double red[4][64];
  const int t = threadIdx.x;
  const int w = t >> 6, l = t & 63;

  // staging roles: w0 A-hi, w1 A-lo, w2 B-hi, w3 B-lo; 8 instr each (8 rows per instr).
  // LDS dest linear: instr q, lane l -> row q*8+(l>>3), part l&7 (16B parts of a 128B row).
  // part p of row r holds global k-part (p ^ (r&7))  [pre-swizzled source, G21/m173]
  const unsigned short* plane = (w & 1) ? plo : phi;
  const int prow0 = (w & 2) ? bj * 64 : bi * 64;
  short* lbase = (w & 2) ? &Bs[w & 1][0][0] : &As[w & 1][0][0];
  const bool skipStage = diag && (w & 2);
  const unsigned short* gbase = plane
      + (size_t)(prow0 + (l >> 3)) * DCOLS + (((l & 7) ^ (l >> 3)) * 8);

  f32x4 acc[4] = {{0.f,0.f,0.f,0.f},{0.f,0.f,0.f,0.f},{0.f,0.f,0.f,0.f},{0.f,0.f,0.f,0.f}};
  double dacc[4][4] = {{0,0,0,0},{0,0,0,0},{0,0,0,0},{0,0,0,0}};

  const int arow = w * 16 + (l & 15);
  const int ar7  = arow & 7;                  // == l&7
  const short* Bsrc0 = diag ? &As[0][0][0] : &Bs[0][0][0];
  const short* Bsrc1 = diag ? &As[1][0][0] : &Bs[1][0][0];

  for (int K0 = 0; K0 < DCOLS; K0 += 2048) {
    for (int k0 = K0; k0 < K0 + 2048; k0 += 64) {
      __syncthreads();                        // previous chunk fully consumed
      if (!skipStage) {
        #pragma unroll
        for (int q = 0; q < 8; ++q)
          GLOAD_LDS16(gbase + (size_t)q * 8 * DCOLS + k0, lbase + q * 512);
      }
      __syncthreads();                        // staging drained
      // A frags: k-step s covers k [s*32, s*32+32); lane part kp = s*4 + (l>>4)
      const int p0 = ((l >> 4)) ^ ar7;        // s=0
      const int p1 = (4 + (l >> 4)) ^ ar7;    // s=1
      short8 ah0 = *(const short8*)&As[0][arow][p0 * 8];
      short8 ah1 = *(const short8*)&As[0][arow][p1 * 8];
      short8 al0 = *(const short8*)&As[1][arow][p0 * 8];
      short8 al1 = *(const short8*)&As[1][arow][p1 * 8];
      #pragma unroll
      for (int cj = 0; cj < 4; ++cj) {
        const int brow = cj * 16 + (l & 15);
        const int q0 = ((l >> 4)) ^ (brow & 7);
        const int q1 = (4 + (l >> 4)) ^ (brow & 7);
        short8 bh0 = *(const short8*)(Bsrc0 + brow * 64 + q0 * 8);
        short8 bh1 = *(const short8*)(Bsrc0 + brow * 64 + q1 * 8);
        short8 bl0 = *(const short8*)(Bsrc1 + brow * 64 + q0 * 8);
        short8 bl1 = *(const short8*)(Bsrc1 + brow * 64 + q1 * 8);
        acc[cj] = __builtin_amdgcn_mfma_f32_16x16x32_bf16(ah0, bh0, acc[cj], 0, 0, 0);
        acc[cj] = __builtin_amdgcn_mfma_f32_16x16x32_bf16(ah1, bh1, acc[cj], 0, 0, 0);
        acc[cj] = __builtin_amdgcn_mfma_f32_16x16x32_bf16(ah0, bl0, acc[cj], 0, 0, 0);
        acc[cj] = __builtin_amdgcn_mfma_f32_16x16x32_bf16(ah1, bl1, acc[cj], 0, 0, 0);
        acc[cj] = __builtin_amdgcn_mfma_f32_16x16x32_bf16(al0, bh0, acc[cj], 0, 0, 0);
        acc[cj] = __builtin_amdgcn_mfma_f32_16x16x32_bf16(al1, bh1, acc[cj], 0, 0, 0);
      }
    }
    #pragma unroll
    for (int cj = 0; cj < 4; ++cj) {
      #pragma unroll
      for (int v = 0; v < 4; ++v) dacc[cj][v] += (double)acc[cj][v];
      acc[cj] = (f32x4){0.f, 0.f, 0.f, 0.f};
    }
  }

  // epilogue. C/D layout: col = lane&15, row = (lane>>4)*4 + v  [m89/m91]
  const int row0 = bi * 64 + w * 16 + (l >> 4) * 4;
  double mr[4], idr[4], mc[4], idc[4];
  #pragma unroll
  for (int v = 0; v < 4; ++v) { mr[v] = m[row0 + v] * 16384.0; idr[v] = 1.0 / dn[row0 + v]; }
  #pragma unroll
  for (int cj = 0; cj < 4; ++cj) {
    int c = bj * 64 + cj * 16 + (l & 15);
    mc[cj] = m[c]; idc[cj] = 1.0 / dn[c];
  }
  double cov[4][4];
  #pragma unroll
  for (int cj = 0; cj < 4; ++cj)
    #pragma unroll
    for (int v = 0; v < 4; ++v)
      cov[cj][v] = dacc[cj][v] - mr[v] * mc[cj];

  // row-direction: s_row[v] = sum_cols |cov| / d_col  -> fpart[bi-tile rows][bj]
  #pragma unroll
  for (int v = 0; v < 4; ++v) {
    double s = 0.0;
    #pragma unroll
    for (int cj = 0; cj < 4; ++cj) s += fabs(cov[cj][v]) * idc[cj];
    s += __shfl_xor(s, 1); s += __shfl_xor(s, 2);
    s += __shfl_xor(s, 4); s += __shfl_xor(s, 8);
    if ((l & 15) == 0)
      fpart[(size_t)(row0 + v) * 16 + bj] = s;
  }
  // col-direction (off-diag only): s_col[cj] = sum_rows |cov| / d_row -> fpart[bj-tile rows][bi]
  if (!diag) {
    #pragma unroll
    for (int cj = 0; cj < 4; ++cj) {
      double sc = 0.0;
      #pragma unroll
      for (int v = 0; v < 4; ++v) sc += fabs(cov[cj][v]) * idr[v];
      sc += __shfl_xor(sc, 16); sc += __shfl_xor(sc, 32);
      if (l < 16) red[w][cj * 16 + l] = sc;
    }
  }
  __syncthreads();
  if (!diag && t < 64) {
    double z = red[0][t] + red[1][t] + red[2][t] + red[3][t];
    fpart[(size_t)(bj * 64 + t) * 16 + bi] = z;
  }
}

// ---- K5c: distributed self-check of fpart (both reduction directions), fp64 exact ----
// blocks 0..15:  verify fpart[r][2], r=0..15  (row-direction from block (0,2))
// blocks 16..79: verify fpart[128+(b-16)][0]  (col-direction from block (0,2))
__global__ __launch_bounds__(256) void k_check2(const float* __restrict__ x,
    const double* __restrict__ m, const double* __restrict__ dn,
    const double* __restrict__ fpart, float* __restrict__ flg) {
  const int b = blockIdx.x;
  const int t = threadIdx.x;
  __shared__ double red[64][4];
  __shared__ double terms[64];
  const int other = t & 63, kq = t >> 6;
  int r, cidx;
  if (b < 16) { r = b; cidx = 128 + other; }           // row r vs cols 128..191
  else        { r = 128 + (b - 16); cidx = other; }    // row j vs rows 0..63
  const float4* xa = (const float4*)(x + (size_t)r * DCOLS) + kq * 1024;
  const float4* xb = (const float4*)(x + (size_t)cidx * DCOLS) + kq * 1024;
  double g = 0.0;
  for (int k = 0; k < 1024; ++k) {
    float4 va = xa[k], vb = xb[k];
    g += (double)va.x * vb.x + (double)va.y * vb.y
       + (double)va.z * vb.z + (double)va.w * vb.w;
  }
  red[other][kq] = g;
  __syncthreads();
  if (t < 64) {
    double G = (red[t][0] + red[t][1]) + (red[t][2] + red[t][3]);
    int oc = (b < 16) ? (128 + t) : t;
    double cov = G - 16384.0 * m[r] * m[oc];
    terms[t] = fabs(cov) / dn[oc];
  }
  __syncthreads();
  if (t == 0) {
    double s = 0.0;
    for (int q = 0; q < 64; ++q) s += terms[q];
    double got = (b < 16) ? fpart[(size_t)r * 16 + 2] : fpart[(size_t)r * 16 + 0];
    if (fabs(got - s) > 2e-3 * fabs(s))
      atomicAdd(flg, (b < 16) ? 1e6f : 2e6f);
  }
}

// ---------------- K5b: fallback fp32-VALU Gram (small ws) ----------------
__global__ __launch_bounds__(256) void k_gram(const float* __restrict__ x,
    const double* __restrict__ m, const double* __restrict__ dn,
    double* __restrict__ fpart) {
  __shared__ float As[32][72];
  __shared__ float Bs[32][72];
  __shared__ double red[64][16];
  const int t = threadIdx.x;
  const int bi = blockIdx.y, bj = blockIdx.x;
  const int tx = t & 15, ty = t >> 4;
  const int lr = t >> 2, lc = t & 3;
  const float* Ap = x + (size_t)(bi * 64 + lr) * DCOLS;
  const float* Bp = x + (size_t)(bj * 64 + lr) * DCOLS;
  double acc[4][4];
  #pragma unroll
  for (int i = 0; i < 4; ++i)
    #pragma unroll
    for (int j = 0; j < 4; ++j) acc[i][j] = 0.0;
  float4 a0 = ((const float4*)Ap)[lc];
  float4 a1 = ((const float4*)Ap)[lc + 4];
  float4 b0 = ((const float4*)Bp)[lc];
  float4 b1 = ((const float4*)Bp)[lc + 4];
  for (int k0 = 0; k0 < DCOLS; k0 += 32) {
    __syncthreads();
    {
      const float* a0p = (const float*)&a0;
      const float* a1p = (const float*)&a1;
      const float* b0p = (const float*)&b0;
      const float* b1p = (const float*)&b1;
      #pragma unroll
      for (int jj = 0; jj < 4; ++jj) {
        As[lc * 4 + jj][lr]      = a0p[jj];
        As[16 + lc * 4 + jj][lr] = a1p[jj];
        Bs[lc * 4 + jj][lr]      = b0p[jj];
        Bs[16 + lc * 4 + jj][lr] = b1p[jj];
      }
    }
    __syncthreads();
    if (k0 + 32 < DCOLS) {
      a0 = ((const float4*)(Ap + k0 + 32))[lc];
      a1 = ((const float4*)(Ap + k0 + 32))[lc + 4];
      b0 = ((const float4*)(Bp + k0 + 32))[lc];
      b1 = ((const float4*)(Bp + k0 + 32))[lc + 4];
    }
    float ac[4][4];
    #pragma unroll
    for (int i = 0; i < 4; ++i)
      #pragma unroll
      for (int j = 0; j < 4; ++j) ac[i][j] = 0.0f;
    #pragma unroll
    for (int k = 0; k < 32; ++k) {
      const float4 av = *(const float4*)&As[k][ty * 4];
      const float4 bv = *(const float4*)&Bs[k][tx * 4];
      const float aa[4] = {av.x, av.y, av.z, av.w};
      const float bb[4] = {bv.x, bv.y, bv.z, bv.w};
      #pragma unroll
      for (int i = 0; i < 4; ++i)
        #pragma unroll
        for (int j = 0; j < 4; ++j)
          ac[i][j] += aa[i] * bb[j];
    }
    #pragma unroll
    for (int i = 0; i < 4; ++i)
      #pragma unroll
      for (int j = 0; j < 4; ++j) acc[i][j] += (double)ac[i][j];
  }
  double mr[4], mc[4], dc[4];
  #pragma unroll
  for (int i = 0; i < 4; ++i) mr[i] = m[bi * 64 + ty * 4 + i];
  #pragma unroll
  for (int j = 0; j < 4; ++j) {
    int col = bj * 64 + tx * 4 + j;
    mc[j] = m[col]; dc[j] = dn[col];
  }
  #pragma unroll
  for (int i = 0; i < 4; ++i) {
    double pi = 0.0;
    #pragma unroll
    for (int j = 0; j < 4; ++j) {
      double cov = acc[i][j] - 16384.0 * mr[i] * mc[j];
      pi += fabs(cov) / dc[j];
    }
    red[ty * 4 + i][tx] = pi;
  }
  __syncthreads();
  if (t < 64) {
    double ssum = 0.0;
    #pragma unroll
    for (int q = 0; q < 16; ++q) ssum += red[t][q];
    fpart[(size_t)(bi * 64 + t) * 16 + bj] = ssum;
  }
}

// ---------------- K3: per-row histogram (float32 np binning) + local entropy ----------------
__global__ __launch_bounds__(256) void k_hist(const float* __restrict__ x,
    const float* __restrict__ fscal, double* __restrict__ localent,
    unsigned* __restrict__ bc) {
#pragma clang fp contract(off)
  __shared__ unsigned h[BINS];
  const int row = blockIdx.x, t = threadIdx.x;
  for (int b = t; b < BINS; b += 256) h[b] = 0;
  __syncthreads();
  const float mu32 = fscal[0], sg32 = fscal[1], lof = fscal[2], wf = fscal[3];
  const float4* xr = (const float4*)(x + (size_t)row * DCOLS);
  for (int j = t; j < DCOLS / 4; j += 256) {
    float4 v = xr[j];
    float vv[4] = {v.x, v.y, v.z, v.w};
    #pragma unroll
    for (int c = 0; c < 4; ++c) {
      float tn = (vv[c] - mu32) / sg32;
      float q  = (tn - lof) / wf;
      int idx = (int)floorf(q);
      idx = idx < 0 ? 0 : (idx > BINS - 1 ? BINS - 1 : idx);
      atomicAdd(&h[idx], 1u);
    }
  }
  __syncthreads();
  const double Dw = (double)fscal[4];
  double ls = 0.0;
  for (int b = t; b < BINS; b += 256) {
    unsigned c = h[b];
    if (c) {
      atomicAdd(&bc[b], c);
      double pd = (double)c / Dw;
      ls -= pd * log2(pd);
    }
  }
  #pragma unroll
  for (int off = 32; off > 0; off >>= 1) ls += __shfl_down(ls, off);
  __shared__ double lsd[4];
  const int lane = t & 63, w = t >> 6;
  if (lane == 0) lsd[w] = ls;
  __syncthreads();
  if (t == 0) localent[row] = (lsd[0] + lsd[1]) + (lsd[2] + lsd[3]);
}

// ---------------- K4: batch entropy + per-row pf / keepf (float32 np chain) ----------------
__global__ __launch_bounds__(256) void k_final(const unsigned* __restrict__ bc,
    const float* __restrict__ fscal, const double* __restrict__ localent,
    const double* __restrict__ fpart, const double* __restrict__ dn,
    float* __restrict__ pf, float* __restrict__ kf) {
#pragma clang fp contract(off)
  const int t = threadIdx.x;
  const double Nw = (double)fscal[5];
  double be = 0.0;
  for (int b = t; b < BINS; b += 256) {
    unsigned c = bc[b];
    if (c) { double pd = (double)c / Nw; be -= pd * log2(pd); }
  }
  #pragma unroll
  for (int off = 32; off > 0; off >>= 1) be += __shfl_down(be, off);
  __shared__ double lsd[4];
  __shared__ double sbent;
  const int lane = t & 63, w = t >> 6;
  if (lane == 0) lsd[w] = be;
  __syncthreads();
  if (t == 0) sbent = (lsd[0] + lsd[1]) + (lsd[2] + lsd[3]);
  __syncthreads();
  const float bef = (float)sbent;
  for (int r = t; r < NROWS; r += 256) {
    double s = 0.0;
    #pragma unroll
    for (int q = 0; q < 16; ++q) s += fpart[(size_t)r * 16 + q];
    float f1f = (float)(s / (dn[r] * 1024.0));
    float lef = (float)localent[r];
    float f2f = lef / bef;
    if (f2f == 0.0f) { f1f = 0.0f; f2f = 1.0f; }
    else if (f2f < 1.0f) f2f = 1.0f / f2f;
    float keepf = f1f / f2f;
    pf[r] = 1.0f - keepf;
    kf[r] = keepf;
  }
}

// ---------------- K6: elementwise masked scale (float32 compare + division) ----------------
__global__ __launch_bounds__(256) void k_apply(const float* __restrict__ x,
    const float* __restrict__ u, const float* __restrict__ pf,
    const float* __restrict__ kf, const float* __restrict__ flg,
    float* __restrict__ out) {
#pragma clang fp contract(off)
  const size_t e = ((size_t)blockIdx.x * 256 + threadIdx.x) * 4;
  const float fl = flg[0];
  if (fl != 0.0f) {           // diagnostic mode: encode check code in out[0]
    float4 o = {0.f, 0.f, 0.f, 0.f};
    if (e == 0) o.x = fl;
    *(float4*)(out + e) = o;
    return;
  }
  const int row = (int)(e >> 14);
  const float pr = pf[row], kr = kf[row];
  const float4 xv = *(const float4*)(x + e);
  const float4 uv = *(const float4*)(u + e);
  float4 o;
  o.x = (uv.x > pr) ? (xv.x / kr) : 0.0f;
  o.y = (uv.y > pr) ? (xv.y / kr) : 0.0f;
  o.z = (uv.z > pr) ? (xv.z / kr) : 0.0f;
  o.w = (uv.w > pr) ? (xv.w / kr) : 0.0f;
  *(float4*)(out + e) = o;
}

extern "C" void kernel_launch(void* const* d_in, const int* in_sizes, int n_in,
                              void* d_out, int out_size, void* d_ws, size_t ws_size,
                              hipStream_t stream) {
  const float* x = (const float*)d_in[0];
  const float* u = (const float*)d_in[1];
  float* out = (float*)d_out;

  const size_t PLANE = (size_t)NROWS * DCOLS * sizeof(unsigned short);  // 32 MB
  const size_t NDBL  = 7 * 1024 + (size_t)NROWS * 16;                   // stats + fpart
  const size_t TAILB = NDBL * 8 + (2056 + 4) * 4 + BINS * 4;
  const bool big = ws_size >= 2 * PLANE + TAILB;

  char* base = (char*)d_ws;
  unsigned short* phi = (unsigned short*)base;
  unsigned short* plo = (unsigned short*)(base + PLANE);
  double* W = big ? (double*)(base + 2 * PLANE) : (double*)base;

  double* rowsum   = W;
  double* rowsumsq = W + 1024;
  double* rowmin   = W + 2048;
  double* rowmax   = W + 3072;
  double* m        = W + 4096;
  double* dn       = W + 5120;
  double* localent = W + 6144;
  double* fpart    = W + 7168;                        // 1024*16 doubles
  float*  F        = (float*)(W + 7168 + (size_t)NROWS * 16);
  float*  pf       = F;
  float*  kf       = F + 1024;
  float*  fscal    = F + 2048;          // 8 floats
  float*  flg      = F + 2056;          // 4 floats
  unsigned* bc     = (unsigned*)(F + 2060);

  hipMemsetAsync(bc, 0, BINS * sizeof(unsigned), stream);

  k_rowstats<<<NROWS, 256, 0, stream>>>(x, rowsum, rowsumsq, rowmin, rowmax);
  k_stats2<<<1, 256, 0, stream>>>(rowsum, rowsumsq, rowmin, rowmax, m, dn, fscal, flg);
  if (big) {
    k_split<<<NTOT / (256 * 8), 256, 0, stream>>>(x, phi, plo);
    k_gramm<<<dim3(16, 16), 256, 0, stream>>>(phi, plo, m, dn, fpart);
    k_check2<<<80, 256, 0, stream>>>(x, m, dn, fpart, flg);
  } else {
    k_gram<<<dim3(16, 16), 256, 0, stream>>>(x, m, dn, fpart);
  }
  k_hist<<<NROWS, 256, 0, stream>>>(x, fscal, localent, bc);
  k_final<<<1, 256, 0, stream>>>(bc, fscal, localent, fpart, dn, pf, kf);
  k_apply<<<NTOT / (256 * 4), 256, 0, stream>>>(x, u, pf, kf, flg, out);
}

// Round 8
// 422.436 us; speedup vs baseline: 3.7639x; 1.1396x over previous
//
#include <hip/hip_runtime.h>
#include <math.h>

#define NROWS 1024
#define DCOLS 16384
#define NTOT  16777216
#define BINS  1000

typedef short short8 __attribute__((ext_vector_type(8)));
typedef unsigned short ushort8 __attribute__((ext_vector_type(8)));
typedef float f32x4 __attribute__((ext_vector_type(4)));

#define GLOAD_LDS16(gp, lp) __builtin_amdgcn_global_load_lds( \
    (const __attribute__((address_space(1))) unsigned int*)(gp), \
    (__attribute__((address_space(3))) unsigned int*)(lp), 16, 0, 0)

// ---------------- K0: fused per-row stats + bf16 hi/lo split (one x pass) ----------------
__global__ __launch_bounds__(256) void k_rowsplit(const float* __restrict__ x,
    unsigned short* __restrict__ phi, unsigned short* __restrict__ plo,
    double* __restrict__ rowsum, double* __restrict__ rowsumsq,
    double* __restrict__ rowmin, double* __restrict__ rowmax) {
  const int row = blockIdx.x, t = threadIdx.x;
  const size_t base = (size_t)row * DCOLS;
  double s = 0.0, s2 = 0.0;
  float mn = 3.4028235e38f, mx = -3.4028235e38f;
  #pragma unroll
  for (int i = 0; i < 8; ++i) {
    const size_t off = base + (size_t)i * 2048 + (size_t)t * 8;
    const float4 v0 = *(const float4*)(x + off);
    const float4 v1 = *(const float4*)(x + off + 4);
    const float vv[8] = {v0.x, v0.y, v0.z, v0.w, v1.x, v1.y, v1.z, v1.w};
    ushort8 h, lo;
    #pragma unroll
    for (int c = 0; c < 8; ++c) {
      unsigned ub = __float_as_uint(vv[c]);
      unsigned hb = (ub + 0x7FFFu + ((ub >> 16) & 1u)) >> 16;   // RNE bf16
      float hf = __uint_as_float(hb << 16);
      float r = vv[c] - hf;                                      // exact
      unsigned ur = __float_as_uint(r);
      unsigned lb = (ur + 0x7FFFu + ((ur >> 16) & 1u)) >> 16;   // RNE bf16
      h[c] = (unsigned short)hb; lo[c] = (unsigned short)lb;
      double dv = vv[c];
      s += dv; s2 += dv * dv;
      mn = fminf(mn, vv[c]); mx = fmaxf(mx, vv[c]);
    }
    *(ushort8*)(phi + off) = h;
    *(ushort8*)(plo + off) = lo;
  }
  #pragma unroll
  for (int off = 32; off > 0; off >>= 1) {
    s  += __shfl_down(s, off);
    s2 += __shfl_down(s2, off);
    mn = fminf(mn, __shfl_down(mn, off));
    mx = fmaxf(mx, __shfl_down(mx, off));
  }
  __shared__ double lsd[8];
  __shared__ float  lsf[8];
  const int lane = t & 63, w = t >> 6;
  if (lane == 0) { lsd[w] = s; lsd[4 + w] = s2; lsf[w] = mn; lsf[4 + w] = mx; }
  __syncthreads();
  if (t == 0) {
    rowsum[row]   = (lsd[0] + lsd[1]) + (lsd[2] + lsd[3]);
    rowsumsq[row] = (lsd[4] + lsd[5]) + (lsd[6] + lsd[7]);
    rowmin[row] = (double)fminf(fminf(lsf[0], lsf[1]), fminf(lsf[2], lsf[3]));
    rowmax[row] = (double)fmaxf(fmaxf(lsf[4], lsf[5]), fmaxf(lsf[6], lsf[7]));
  }
}

// ---------------- K1 (fallback path only): per-row stats without split ----------------
__global__ __launch_bounds__(256) void k_rowstats(const float* __restrict__ x,
    double* __restrict__ rowsum, double* __restrict__ rowsumsq,
    double* __restrict__ rowmin, double* __restrict__ rowmax) {
  const int row = blockIdx.x;
  const int t = threadIdx.x;
  const float4* xr = (const float4*)(x + (size_t)row * DCOLS);
  double s = 0.0, s2 = 0.0;
  float mn = 3.4028235e38f, mx = -3.4028235e38f;
  for (int j = t; j < DCOLS / 4; j += 256) {
    float4 v = xr[j];
    double a = v.x, b = v.y, c = v.z, d = v.w;
    s  += (a + b) + (c + d);
    s2 += (a * a + b * b) + (c * c + d * d);
    mn = fminf(mn, fminf(fminf(v.x, v.y), fminf(v.z, v.w)));
    mx = fmaxf(mx, fmaxf(fmaxf(v.x, v.y), fmaxf(v.z, v.w)));
  }
  #pragma unroll
  for (int off = 32; off > 0; off >>= 1) {
    s  += __shfl_down(s, off);
    s2 += __shfl_down(s2, off);
    mn = fminf(mn, __shfl_down(mn, off));
    mx = fmaxf(mx, __shfl_down(mx, off));
  }
  __shared__ double lsd[8];
  __shared__ float  lsf[8];
  const int lane = t & 63, w = t >> 6;
  if (lane == 0) { lsd[w] = s; lsd[4 + w] = s2; lsf[w] = mn; lsf[4 + w] = mx; }
  __syncthreads();
  if (t == 0) {
    rowsum[row]   = (lsd[0] + lsd[1]) + (lsd[2] + lsd[3]);
    rowsumsq[row] = (lsd[4] + lsd[5]) + (lsd[6] + lsd[7]);
    rowmin[row] = (double)fminf(fminf(lsf[0], lsf[1]), fminf(lsf[2], lsf[3]));
    rowmax[row] = (double)fmaxf(fmaxf(lsf[4], lsf[5]), fmaxf(lsf[6], lsf[7]));
  }
}

// ---------------- K2: global scalars (fp64 stats -> float32 np-style scalars) + bc zero ----------------
__global__ __launch_bounds__(256) void k_stats2(
    const double* __restrict__ rowsum, const double* __restrict__ rowsumsq,
    const double* __restrict__ rowmin, const double* __restrict__ rowmax,
    double* __restrict__ m, double* __restrict__ dn, float* __restrict__ fscal,
    float* __restrict__ flg, unsigned* __restrict__ bc) {
#pragma clang fp contract(off)
  const int t = threadIdx.x;
  for (int b = t; b < BINS; b += 256) bc[b] = 0;   // replaces hipMemsetAsync
  double s = 0.0, s2 = 0.0, mn = 1e300, mx = -1e300;
  for (int r = t; r < NROWS; r += 256) {
    s += rowsum[r]; s2 += rowsumsq[r];
    mn = fmin(mn, rowmin[r]); mx = fmax(mx, rowmax[r]);
  }
  #pragma unroll
  for (int off = 32; off > 0; off >>= 1) {
    s  += __shfl_down(s, off);
    s2 += __shfl_down(s2, off);
    mn = fmin(mn, __shfl_down(mn, off));
    mx = fmax(mx, __shfl_down(mx, off));
  }
  __shared__ double lsd[16];
  const int lane = t & 63, w = t >> 6;
  if (lane == 0) { lsd[w] = s; lsd[4 + w] = s2; lsd[8 + w] = mn; lsd[12 + w] = mx; }
  __syncthreads();
  if (t == 0) {
    double S  = (lsd[0] + lsd[1]) + (lsd[2] + lsd[3]);
    double S2 = (lsd[4] + lsd[5]) + (lsd[6] + lsd[7]);
    double MN = fmin(fmin(lsd[8], lsd[9]), fmin(lsd[10], lsd[11]));
    double MX = fmax(fmax(lsd[12], lsd[13]), fmax(lsd[14], lsd[15]));
    const double N = 16777216.0;
    double mu  = S / N;
    double var = (S2 - S * S / N) / (N - 1.0);
    double sig = sqrt(var);
    float mu32 = (float)mu;
    float sg32 = (float)sig;
    float mnf  = (float)MN;
    float mxf  = (float)MX;
    float lof  = (mnf - mu32) / sg32;
    float hif  = (mxf - mu32) / sg32;
    float wf   = (hif - lof) / 1000.0f;
    fscal[0] = mu32;
    fscal[1] = sg32;
    fscal[2] = lof;
    fscal[3] = wf;
    fscal[4] = 16384.0f * wf;
    fscal[5] = 16777216.0f * wf;
    flg[0] = 0.0f;
  }
  __syncthreads();
  for (int r = t; r < NROWS; r += 256) {
    double rs = rowsum[r];
    m[r]  = rs / 16384.0;
    dn[r] = sqrt(rowsumsq[r] - rs * rs * (1.0 / 16384.0));
  }
}

// ---- K5a: MFMA Gram, 64x64 tile, upper-triangle, BK=64, XOR-swizzled LDS,
// ----      2-deep double-buffer with counted vmcnt + raw barriers (T3/T4 minimal) ----
__global__ __launch_bounds__(256) void k_gramm(
    const unsigned short* __restrict__ phi, const unsigned short* __restrict__ plo,
    const double* __restrict__ m, const double* __restrict__ dn,
    double* __restrict__ fpart) {
  const int bi = blockIdx.y, bj = blockIdx.x;
  if (bj < bi) return;                       // upper triangle only
  const bool diag = (bi == bj);
  __shared__ short As[2][2][64][64];         // [buf][plane][row][k] — 64 KB
  __shared__ short Bs[2][2][64][64];         // 64 KB
  __shared__ double red[4][64];
  const int t = threadIdx.x;
  const int w = t >> 6, l = t & 63;

  // staging roles: w0 A-hi, w1 A-lo, w2 B-hi, w3 B-lo; 8 instr each (8 rows per instr).
  // LDS dest linear: instr q, lane l -> row q*8+(l>>3), part l&7 (16B parts of 128B row).
  // part p of row r holds global k-part (p ^ (r&7))  [pre-swizzled source]
  const unsigned short* plane = (w & 1) ? plo : phi;
  const int prow0 = (w & 2) ? bj * 64 : bi * 64;
  const bool skipStage = diag && (w & 2);
  const unsigned short* gbase = plane
      + (size_t)(prow0 + (l >> 3)) * DCOLS + (((l & 7) ^ (l >> 3)) * 8);
  short* lbm = (w & 2) ? &Bs[0][0][0][0] : &As[0][0][0][0];
  short* lb0 = lbm + (w & 1) * 4096;         // buf 0, my plane
  short* lb1 = lb0 + 8192;                   // buf 1

#define STAGE(dst, kk) do { if (!skipStage) { \
    _Pragma("unroll") \
    for (int q = 0; q < 8; ++q) \
      GLOAD_LDS16(gbase + (size_t)q * 8 * DCOLS + (kk), (dst) + q * 512); \
  } } while (0)

  f32x4 acc[4] = {{0.f,0.f,0.f,0.f},{0.f,0.f,0.f,0.f},{0.f,0.f,0.f,0.f},{0.f,0.f,0.f,0.f}};
  double dacc[4][4] = {{0,0,0,0},{0,0,0,0},{0,0,0,0},{0,0,0,0}};

  const int arow = w * 16 + (l & 15);
  const int ar7  = arow & 7;
  const int p0 = (l >> 4) ^ ar7;             // kstep 0 part
  const int p1 = (4 + (l >> 4)) ^ ar7;       // kstep 1 part

  STAGE(lb0, 0);                             // prologue: chunk 0 -> buf 0
  int cur = 0;
  for (int tc = 0; tc < 256; ++tc) {
    if (tc < 255) {
      STAGE(cur ? lb0 : lb1, (tc + 1) * 64); // issue next chunk into other buf
      asm volatile("s_waitcnt vmcnt(8)" ::: "memory");  // my chunk-tc loads landed
    } else {
      asm volatile("s_waitcnt vmcnt(0)" ::: "memory");
    }
    __builtin_amdgcn_s_barrier();            // all waves' chunk-tc loads landed
    __builtin_amdgcn_sched_barrier(0);       // rule #18: no ds_read hoisted above
    {
      const int coff = cur * 8192;
      const short* A0 = &As[0][0][0][0] + coff;
      const short* A1 = A0 + 4096;
      const short* B0 = diag ? A0 : (&Bs[0][0][0][0] + coff);
      const short* B1 = diag ? A1 : (&Bs[0][0][0][0] + coff + 4096);
      short8 ah0 = *(const short8*)(A0 + arow * 64 + p0 * 8);
      short8 ah1 = *(const short8*)(A0 + arow * 64 + p1 * 8);
      short8 al0 = *(const short8*)(A1 + arow * 64 + p0 * 8);
      short8 al1 = *(const short8*)(A1 + arow * 64 + p1 * 8);
      #pragma unroll
      for (int cj = 0; cj < 4; ++cj) {
        const int brow = cj * 16 + (l & 15);
        const int q0 = ((l >> 4)) ^ (brow & 7);
        const int q1 = (4 + (l >> 4)) ^ (brow & 7);
        short8 bh0 = *(const short8*)(B0 + brow * 64 + q0 * 8);
        short8 bh1 = *(const short8*)(B0 + brow * 64 + q1 * 8);
        short8 bl0 = *(const short8*)(B1 + brow * 64 + q0 * 8);
        short8 bl1 = *(const short8*)(B1 + brow * 64 + q1 * 8);
        acc[cj] = __builtin_amdgcn_mfma_f32_16x16x32_bf16(ah0, bh0, acc[cj], 0, 0, 0);
        acc[cj] = __builtin_amdgcn_mfma_f32_16x16x32_bf16(ah1, bh1, acc[cj], 0, 0, 0);
        acc[cj] = __builtin_amdgcn_mfma_f32_16x16x32_bf16(ah0, bl0, acc[cj], 0, 0, 0);
        acc[cj] = __builtin_amdgcn_mfma_f32_16x16x32_bf16(ah1, bl1, acc[cj], 0, 0, 0);
        acc[cj] = __builtin_amdgcn_mfma_f32_16x16x32_bf16(al0, bh0, acc[cj], 0, 0, 0);
        acc[cj] = __builtin_amdgcn_mfma_f32_16x16x32_bf16(al1, bh1, acc[cj], 0, 0, 0);
      }
    }
    __builtin_amdgcn_sched_barrier(0);       // pin reads+MFMA before the barrier
    __builtin_amdgcn_s_barrier();            // all reads done -> buf reusable
    if ((tc & 31) == 31) {                   // fold every K=2048 (same cadence as r7)
      #pragma unroll
      for (int cj = 0; cj < 4; ++cj) {
        #pragma unroll
        for (int v = 0; v < 4; ++v) dacc[cj][v] += (double)acc[cj][v];
        acc[cj] = (f32x4){0.f, 0.f, 0.f, 0.f};
      }
    }
    cur ^= 1;
  }
#undef STAGE

  // epilogue. C/D layout: col = lane&15, row = (lane>>4)*4 + v
  const int row0 = bi * 64 + w * 16 + (l >> 4) * 4;
  double mr[4], idr[4], mc[4], idc[4];
  #pragma unroll
  for (int v = 0; v < 4; ++v) { mr[v] = m[row0 + v] * 16384.0; idr[v] = 1.0 / dn[row0 + v]; }
  #pragma unroll
  for (int cj = 0; cj < 4; ++cj) {
    int c = bj * 64 + cj * 16 + (l & 15);
    mc[cj] = m[c]; idc[cj] = 1.0 / dn[c];
  }
  double cov[4][4];
  #pragma unroll
  for (int cj = 0; cj < 4; ++cj)
    #pragma unroll
    for (int v = 0; v < 4; ++v)
      cov[cj][v] = dacc[cj][v] - mr[v] * mc[cj];

  #pragma unroll
  for (int v = 0; v < 4; ++v) {
    double s = 0.0;
    #pragma unroll
    for (int cj = 0; cj < 4; ++cj) s += fabs(cov[cj][v]) * idc[cj];
    s += __shfl_xor(s, 1); s += __shfl_xor(s, 2);
    s += __shfl_xor(s, 4); s += __shfl_xor(s, 8);
    if ((l & 15) == 0)
      fpart[(size_t)(row0 + v) * 16 + bj] = s;
  }
  if (!diag) {
    #pragma unroll
    for (int cj = 0; cj < 4; ++cj) {
      double sc = 0.0;
      #pragma unroll
      for (int v = 0; v < 4; ++v) sc += fabs(cov[cj][v]) * idr[v];
      sc += __shfl_xor(sc, 16); sc += __shfl_xor(sc, 32);
      if (l < 16) red[w][cj * 16 + l] = sc;
    }
  }
  __syncthreads();
  if (!diag && t < 64) {
    double z = red[0][t] + red[1][t] + red[2][t] + red[3][t];
    fpart[(size_t)(bj * 64 + t) * 16 + bi] = z;
  }
}

// ---- K5c: distributed self-check of fpart (both reduction directions), fp64 exact ----
__global__ __launch_bounds__(256) void k_check2(const float* __restrict__ x,
    const double* __restrict__ m, const double* __restrict__ dn,
    const double* __restrict__ fpart, float* __restrict__ flg) {
  const int b = blockIdx.x;
  const int t = threadIdx.x;
  __shared__ double red[64][4];
  __shared__ double terms[64];
  const int other = t & 63, kq = t >> 6;
  int r, cidx;
  if (b < 16) { r = b; cidx = 128 + other; }           // row r vs cols 128..191
  else        { r = 128 + (b - 16); cidx = other; }    // row j vs rows 0..63
  const float4* xa = (const float4*)(x + (size_t)r * DCOLS) + kq * 1024;
  const float4* xb = (const float4*)(x + (size_t)cidx * DCOLS) + kq * 1024;
  double g = 0.0;
  for (int k = 0; k < 1024; ++k) {
    float4 va = xa[k], vb = xb[k];
    g += (double)va.x * vb.x + (double)va.y * vb.y
       + (double)va.z * vb.z + (double)va.w * vb.w;
  }
  red[other][kq] = g;
  __syncthreads();
  if (t < 64) {
    double G = (red[t][0] + red[t][1]) + (red[t][2] + red[t][3]);
    int oc = (b < 16) ? (128 + t) : t;
    double cov = G - 16384.0 * m[r] * m[oc];
    terms[t] = fabs(cov) / dn[oc];
  }
  __syncthreads();
  if (t == 0) {
    double s = 0.0;
    for (int q = 0; q < 64; ++q) s += terms[q];
    double got = (b < 16) ? fpart[(size_t)r * 16 + 2] : fpart[(size_t)r * 16 + 0];
    if (fabs(got - s) > 2e-3 * fabs(s))
      atomicAdd(flg, (b < 16) ? 1e6f : 2e6f);
  }
}

// ---------------- K5b: fallback fp32-VALU Gram (small ws) ----------------
__global__ __launch_bounds__(256) void k_gram(const float* __restrict__ x,
    const double* __restrict__ m, const double* __restrict__ dn,
    double* __restrict__ fpart) {
  __shared__ float As[32][72];
  __shared__ float Bs[32][72];
  __shared__ double red[64][16];
  const int t = threadIdx.x;
  const int bi = blockIdx.y, bj = blockIdx.x;
  const int tx = t & 15, ty = t >> 4;
  const int lr = t >> 2, lc = t & 3;
  const float* Ap = x + (size_t)(bi * 64 + lr) * DCOLS;
  const float* Bp = x + (size_t)(bj * 64 + lr) * DCOLS;
  double acc[4][4];
  #pragma unroll
  for (int i = 0; i < 4; ++i)
    #pragma unroll
    for (int j = 0; j < 4; ++j) acc[i][j] = 0.0;
  float4 a0 = ((const float4*)Ap)[lc];
  float4 a1 = ((const float4*)Ap)[lc + 4];
  float4 b0 = ((const float4*)Bp)[lc];
  float4 b1 = ((const float4*)Bp)[lc + 4];
  for (int k0 = 0; k0 < DCOLS; k0 += 32) {
    __syncthreads();
    {
      const float* a0p = (const float*)&a0;
      const float* a1p = (const float*)&a1;
      const float* b0p = (const float*)&b0;
      const float* b1p = (const float*)&b1;
      #pragma unroll
      for (int jj = 0; jj < 4; ++jj) {
        As[lc * 4 + jj][lr]      = a0p[jj];
        As[16 + lc * 4 + jj][lr] = a1p[jj];
        Bs[lc * 4 + jj][lr]      = b0p[jj];
        Bs[16 + lc * 4 + jj][lr] = b1p[jj];
      }
    }
    __syncthreads();
    if (k0 + 32 < DCOLS) {
      a0 = ((const float4*)(Ap + k0 + 32))[lc];
      a1 = ((const float4*)(Ap + k0 + 32))[lc + 4];
      b0 = ((const float4*)(Bp + k0 + 32))[lc];
      b1 = ((const float4*)(Bp + k0 + 32))[lc + 4];
    }
    float ac[4][4];
    #pragma unroll
    for (int i = 0; i < 4; ++i)
      #pragma unroll
      for (int j = 0; j < 4; ++j) ac[i][j] = 0.0f;
    #pragma unroll
    for (int k = 0; k < 32; ++k) {
      const float4 av = *(const float4*)&As[k][ty * 4];
      const float4 bv = *(const float4*)&Bs[k][tx * 4];
      const float aa[4] = {av.x, av.y, av.z, av.w};
      const float bb[4] = {bv.x, bv.y, bv.z, bv.w};
      #pragma unroll
      for (int i = 0; i < 4; ++i)
        #pragma unroll
        for (int j = 0; j < 4; ++j)
          ac[i][j] += aa[i] * bb[j];
    }
    #pragma unroll
    for (int i = 0; i < 4; ++i)
      #pragma unroll
      for (int j = 0; j < 4; ++j) acc[i][j] += (double)ac[i][j];
  }
  double mr[4], mc[4], dc[4];
  #pragma unroll
  for (int i = 0; i < 4; ++i) mr[i] = m[bi * 64 + ty * 4 + i];
  #pragma unroll
  for (int j = 0; j < 4; ++j) {
    int col = bj * 64 + tx * 4 + j;
    mc[j] = m[col]; dc[j] = dn[col];
  }
  #pragma unroll
  for (int i = 0; i < 4; ++i) {
    double pi = 0.0;
    #pragma unroll
    for (int j = 0; j < 4; ++j) {
      double cov = acc[i][j] - 16384.0 * mr[i] * mc[j];
      pi += fabs(cov) / dc[j];
    }
    red[ty * 4 + i][tx] = pi;
  }
  __syncthreads();
  if (t < 64) {
    double ssum = 0.0;
    #pragma unroll
    for (int q = 0; q < 16; ++q) ssum += red[t][q];
    fpart[(size_t)(bi * 64 + t) * 16 + bj] = ssum;
  }
}

// ---------------- K3: per-row histogram (float32 np binning) + local entropy ----------------
__global__ __launch_bounds__(256) void k_hist(const float* __restrict__ x,
    const float* __restrict__ fscal, double* __restrict__ localent,
    unsigned* __restrict__ bc) {
#pragma clang fp contract(off)
  __shared__ unsigned h[BINS];
  const int row = blockIdx.x, t = threadIdx.x;
  for (int b = t; b < BINS; b += 256) h[b] = 0;
  __syncthreads();
  const float mu32 = fscal[0], sg32 = fscal[1], lof = fscal[2], wf = fscal[3];
  const float4* xr = (const float4*)(x + (size_t)row * DCOLS);
  for (int j = t; j < DCOLS / 4; j += 256) {
    float4 v = xr[j];
    float vv[4] = {v.x, v.y, v.z, v.w};
    #pragma unroll
    for (int c = 0; c < 4; ++c) {
      float tn = (vv[c] - mu32) / sg32;
      float q  = (tn - lof) / wf;
      int idx = (int)floorf(q);
      idx = idx < 0 ? 0 : (idx > BINS - 1 ? BINS - 1 : idx);
      atomicAdd(&h[idx], 1u);
    }
  }
  __syncthreads();
  const double Dw = (double)fscal[4];
  double ls = 0.0;
  for (int b = t; b < BINS; b += 256) {
    unsigned c = h[b];
    if (c) {
      atomicAdd(&bc[b], c);
      double pd = (double)c / Dw;
      ls -= pd * log2(pd);
    }
  }
  #pragma unroll
  for (int off = 32; off > 0; off >>= 1) ls += __shfl_down(ls, off);
  __shared__ double lsd[4];
  const int lane = t & 63, w = t >> 6;
  if (lane == 0) lsd[w] = ls;
  __syncthreads();
  if (t == 0) localent[row] = (lsd[0] + lsd[1]) + (lsd[2] + lsd[3]);
}

// ---------------- K4: batch entropy + per-row pf / keepf (float32 np chain) ----------------
__global__ __launch_bounds__(256) void k_final(const unsigned* __restrict__ bc,
    const float* __restrict__ fscal, const double* __restrict__ localent,
    const double* __restrict__ fpart, const double* __restrict__ dn,
    float* __restrict__ pf, float* __restrict__ kf) {
#pragma clang fp contract(off)
  const int t = threadIdx.x;
  const double Nw = (double)fscal[5];
  double be = 0.0;
  for (int b = t; b < BINS; b += 256) {
    unsigned c = bc[b];
    if (c) { double pd = (double)c / Nw; be -= pd * log2(pd); }
  }
  #pragma unroll
  for (int off = 32; off > 0; off >>= 1) be += __shfl_down(be, off);
  __shared__ double lsd[4];
  __shared__ double sbent;
  const int lane = t & 63, w = t >> 6;
  if (lane == 0) lsd[w] = be;
  __syncthreads();
  if (t == 0) sbent = (lsd[0] + lsd[1]) + (lsd[2] + lsd[3]);
  __syncthreads();
  const float bef = (float)sbent;
  for (int r = t; r < NROWS; r += 256) {
    double s = 0.0;
    #pragma unroll
    for (int q = 0; q < 16; ++q) s += fpart[(size_t)r * 16 + q];
    float f1f = (float)(s / (dn[r] * 1024.0));
    float lef = (float)localent[r];
    float f2f = lef / bef;
    if (f2f == 0.0f) { f1f = 0.0f; f2f = 1.0f; }
    else if (f2f < 1.0f) f2f = 1.0f / f2f;
    float keepf = f1f / f2f;
    pf[r] = 1.0f - keepf;
    kf[r] = keepf;
  }
}

// ---------------- K6: elementwise masked scale (float32 compare + division) ----------------
__global__ __launch_bounds__(256) void k_apply(const float* __restrict__ x,
    const float* __restrict__ u, const float* __restrict__ pf,
    const float* __restrict__ kf, const float* __restrict__ flg,
    float* __restrict__ out) {
#pragma clang fp contract(off)
  const size_t e = ((size_t)blockIdx.x * 256 + threadIdx.x) * 4;
  const float fl = flg[0];
  if (fl != 0.0f) {           // diagnostic mode: encode check code in out[0]
    float4 o = {0.f, 0.f, 0.f, 0.f};
    if (e == 0) o.x = fl;
    *(float4*)(out + e) = o;
    return;
  }
  const int row = (int)(e >> 14);
  const float pr = pf[row], kr = kf[row];
  const float4 xv = *(const float4*)(x + e);
  const float4 uv = *(const float4*)(u + e);
  float4 o;
  o.x = (uv.x > pr) ? (xv.x / kr) : 0.0f;
  o.y = (uv.y > pr) ? (xv.y / kr) : 0.0f;
  o.z = (uv.z > pr) ? (xv.z / kr) : 0.0f;
  o.w = (uv.w > pr) ? (xv.w / kr) : 0.0f;
  *(float4*)(out + e) = o;
}

extern "C" void kernel_launch(void* const* d_in, const int* in_sizes, int n_in,
                              void* d_out, int out_size, void* d_ws, size_t ws_size,
                              hipStream_t stream) {
  const float* x = (const float*)d_in[0];
  const float* u = (const float*)d_in[1];
  float* out = (float*)d_out;

  const size_t PLANE = (size_t)NROWS * DCOLS * sizeof(unsigned short);  // 32 MB
  const size_t NDBL  = 7 * 1024 + (size_t)NROWS * 16;                   // stats + fpart
  const size_t TAILB = NDBL * 8 + (2056 + 4) * 4 + BINS * 4;
  const bool big = ws_size >= 2 * PLANE + TAILB;

  char* base = (char*)d_ws;
  unsigned short* phi = (unsigned short*)base;
  unsigned short* plo = (unsigned short*)(base + PLANE);
  double* W = big ? (double*)(base + 2 * PLANE) : (double*)base;

  double* rowsum   = W;
  double* rowsumsq = W + 1024;
  double* rowmin   = W + 2048;
  double* rowmax   = W + 3072;
  double* m        = W + 4096;
  double* dn       = W + 5120;
  double* localent = W + 6144;
  double* fpart    = W + 7168;                        // 1024*16 doubles
  float*  F        = (float*)(W + 7168 + (size_t)NROWS * 16);
  float*  pf       = F;
  float*  kf       = F + 1024;
  float*  fscal    = F + 2048;          // 8 floats
  float*  flg      = F + 2056;          // 4 floats
  unsigned* bc     = (unsigned*)(F + 2060);

  if (big) {
    k_rowsplit<<<NROWS, 256, 0, stream>>>(x, phi, plo, rowsum, rowsumsq, rowmin, rowmax);
    k_stats2<<<1, 256, 0, stream>>>(rowsum, rowsumsq, rowmin, rowmax, m, dn, fscal, flg, bc);
    k_gramm<<<dim3(16, 16), 256, 0, stream>>>(phi, plo, m, dn, fpart);
    k_check2<<<80, 256, 0, stream>>>(x, m, dn, fpart, flg);
  } else {
    k_rowstats<<<NROWS, 256, 0, stream>>>(x, rowsum, rowsumsq, rowmin, rowmax);
    k_stats2<<<1, 256, 0, stream>>>(rowsum, rowsumsq, rowmin, rowmax, m, dn, fscal, flg, bc);
    k_gram<<<dim3(16, 16), 256, 0, stream>>>(x, m, dn, fpart);
  }
  k_hist<<<NROWS, 256, 0, stream>>>(x, fscal, localent, bc);
  k_final<<<1, 256, 0, stream>>>(bc, fscal, localent, fpart, dn, pf, kf);
  k_apply<<<NTOT / (256 * 4), 256, 0, stream>>>(x, u, pf, kf, flg, out);
}

// Round 9
// 329.481 us; speedup vs baseline: 4.8258x; 1.2821x over previous
//
#include <hip/hip_runtime.h>
#include <math.h>

#define NROWS 1024
#define DCOLS 16384
#define NTOT  16777216
#define BINS  1000
#define NPAIR 136   // 16*17/2 upper-triangle 64x64 tile pairs

typedef short short8 __attribute__((ext_vector_type(8)));
typedef unsigned short ushort8 __attribute__((ext_vector_type(8)));
typedef float f32x4 __attribute__((ext_vector_type(4)));

#define GLOAD_LDS16(gp, lp) __builtin_amdgcn_global_load_lds( \
    (const __attribute__((address_space(1))) unsigned int*)(gp), \
    (__attribute__((address_space(3))) unsigned int*)(lp), 16, 0, 0)

// ---------------- K0: fused per-row stats + bf16 hi/lo split (one x pass) ----------------
__global__ __launch_bounds__(256) void k_rowsplit(const float* __restrict__ x,
    unsigned short* __restrict__ phi, unsigned short* __restrict__ plo,
    double* __restrict__ rowsum, double* __restrict__ rowsumsq,
    double* __restrict__ rowmin, double* __restrict__ rowmax) {
  const int row = blockIdx.x, t = threadIdx.x;
  const size_t base = (size_t)row * DCOLS;
  double s = 0.0, s2 = 0.0;
  float mn = 3.4028235e38f, mx = -3.4028235e38f;
  #pragma unroll
  for (int i = 0; i < 8; ++i) {
    const size_t off = base + (size_t)i * 2048 + (size_t)t * 8;
    const float4 v0 = *(const float4*)(x + off);
    const float4 v1 = *(const float4*)(x + off + 4);
    const float vv[8] = {v0.x, v0.y, v0.z, v0.w, v1.x, v1.y, v1.z, v1.w};
    ushort8 h, lo;
    #pragma unroll
    for (int c = 0; c < 8; ++c) {
      unsigned ub = __float_as_uint(vv[c]);
      unsigned hb = (ub + 0x7FFFu + ((ub >> 16) & 1u)) >> 16;   // RNE bf16
      float hf = __uint_as_float(hb << 16);
      float r = vv[c] - hf;                                      // exact
      unsigned ur = __float_as_uint(r);
      unsigned lb = (ur + 0x7FFFu + ((ur >> 16) & 1u)) >> 16;   // RNE bf16
      h[c] = (unsigned short)hb; lo[c] = (unsigned short)lb;
      double dv = vv[c];
      s += dv; s2 += dv * dv;
      mn = fminf(mn, vv[c]); mx = fmaxf(mx, vv[c]);
    }
    *(ushort8*)(phi + off) = h;
    *(ushort8*)(plo + off) = lo;
  }
  #pragma unroll
  for (int off = 32; off > 0; off >>= 1) {
    s  += __shfl_down(s, off);
    s2 += __shfl_down(s2, off);
    mn = fminf(mn, __shfl_down(mn, off));
    mx = fmaxf(mx, __shfl_down(mx, off));
  }
  __shared__ double lsd[8];
  __shared__ float  lsf[8];
  const int lane = t & 63, w = t >> 6;
  if (lane == 0) { lsd[w] = s; lsd[4 + w] = s2; lsf[w] = mn; lsf[4 + w] = mx; }
  __syncthreads();
  if (t == 0) {
    rowsum[row]   = (lsd[0] + lsd[1]) + (lsd[2] + lsd[3]);
    rowsumsq[row] = (lsd[4] + lsd[5]) + (lsd[6] + lsd[7]);
    rowmin[row] = (double)fminf(fminf(lsf[0], lsf[1]), fminf(lsf[2], lsf[3]));
    rowmax[row] = (double)fmaxf(fmaxf(lsf[4], lsf[5]), fmaxf(lsf[6], lsf[7]));
  }
}

// ---------------- K1 (fallback path only): per-row stats without split ----------------
__global__ __launch_bounds__(256) void k_rowstats(const float* __restrict__ x,
    double* __restrict__ rowsum, double* __restrict__ rowsumsq,
    double* __restrict__ rowmin, double* __restrict__ rowmax) {
  const int row = blockIdx.x;
  const int t = threadIdx.x;
  const float4* xr = (const float4*)(x + (size_t)row * DCOLS);
  double s = 0.0, s2 = 0.0;
  float mn = 3.4028235e38f, mx = -3.4028235e38f;
  for (int j = t; j < DCOLS / 4; j += 256) {
    float4 v = xr[j];
    double a = v.x, b = v.y, c = v.z, d = v.w;
    s  += (a + b) + (c + d);
    s2 += (a * a + b * b) + (c * c + d * d);
    mn = fminf(mn, fminf(fminf(v.x, v.y), fminf(v.z, v.w)));
    mx = fmaxf(mx, fmaxf(fmaxf(v.x, v.y), fmaxf(v.z, v.w)));
  }
  #pragma unroll
  for (int off = 32; off > 0; off >>= 1) {
    s  += __shfl_down(s, off);
    s2 += __shfl_down(s2, off);
    mn = fminf(mn, __shfl_down(mn, off));
    mx = fmaxf(mx, __shfl_down(mx, off));
  }
  __shared__ double lsd[8];
  __shared__ float  lsf[8];
  const int lane = t & 63, w = t >> 6;
  if (lane == 0) { lsd[w] = s; lsd[4 + w] = s2; lsf[w] = mn; lsf[4 + w] = mx; }
  __syncthreads();
  if (t == 0) {
    rowsum[row]   = (lsd[0] + lsd[1]) + (lsd[2] + lsd[3]);
    rowsumsq[row] = (lsd[4] + lsd[5]) + (lsd[6] + lsd[7]);
    rowmin[row] = (double)fminf(fminf(lsf[0], lsf[1]), fminf(lsf[2], lsf[3]));
    rowmax[row] = (double)fmaxf(fmaxf(lsf[4], lsf[5]), fmaxf(lsf[6], lsf[7]));
  }
}

// ---------------- K2: global scalars (fp64 stats -> float32 np-style scalars) + bc zero ----------------
__global__ __launch_bounds__(256) void k_stats2(
    const double* __restrict__ rowsum, const double* __restrict__ rowsumsq,
    const double* __restrict__ rowmin, const double* __restrict__ rowmax,
    double* __restrict__ m, double* __restrict__ dn, float* __restrict__ fscal,
    float* __restrict__ flg, unsigned* __restrict__ bc) {
#pragma clang fp contract(off)
  const int t = threadIdx.x;
  for (int b = t; b < BINS; b += 256) bc[b] = 0;
  double s = 0.0, s2 = 0.0, mn = 1e300, mx = -1e300;
  for (int r = t; r < NROWS; r += 256) {
    s += rowsum[r]; s2 += rowsumsq[r];
    mn = fmin(mn, rowmin[r]); mx = fmax(mx, rowmax[r]);
  }
  #pragma unroll
  for (int off = 32; off > 0; off >>= 1) {
    s  += __shfl_down(s, off);
    s2 += __shfl_down(s2, off);
    mn = fmin(mn, __shfl_down(mn, off));
    mx = fmax(mx, __shfl_down(mx, off));
  }
  __shared__ double lsd[16];
  const int lane = t & 63, w = t >> 6;
  if (lane == 0) { lsd[w] = s; lsd[4 + w] = s2; lsd[8 + w] = mn; lsd[12 + w] = mx; }
  __syncthreads();
  if (t == 0) {
    double S  = (lsd[0] + lsd[1]) + (lsd[2] + lsd[3]);
    double S2 = (lsd[4] + lsd[5]) + (lsd[6] + lsd[7]);
    double MN = fmin(fmin(lsd[8], lsd[9]), fmin(lsd[10], lsd[11]));
    double MX = fmax(fmax(lsd[12], lsd[13]), fmax(lsd[14], lsd[15]));
    const double N = 16777216.0;
    double mu  = S / N;
    double var = (S2 - S * S / N) / (N - 1.0);
    double sig = sqrt(var);
    float mu32 = (float)mu;
    float sg32 = (float)sig;
    float mnf  = (float)MN;
    float mxf  = (float)MX;
    float lof  = (mnf - mu32) / sg32;
    float hif  = (mxf - mu32) / sg32;
    float wf   = (hif - lof) / 1000.0f;
    fscal[0] = mu32;
    fscal[1] = sg32;
    fscal[2] = lof;
    fscal[3] = wf;
    fscal[4] = 16384.0f * wf;
    fscal[5] = 16777216.0f * wf;
    flg[0] = 0.0f;
  }
  __syncthreads();
  for (int r = t; r < NROWS; r += 256) {
    double rs = rowsum[r];
    m[r]  = rs / 16384.0;
    dn[r] = sqrt(rowsumsq[r] - rs * rs * (1.0 / 16384.0));
  }
}

// ---- K5a: split-K MFMA Gram. 544 blocks = 136 pairs x 4 K-quarters (K=4096 each).
// ---- Single-buffer LDS (64 KB -> 2 blocks/CU), r7-proven loop + swizzle.
// ---- Writes fp32 partial Gram slice to Gs[(pid*4+ks)*4096 + row*64 + col].
__global__ __launch_bounds__(256) void k_gramm_sk(
    const unsigned short* __restrict__ phi, const unsigned short* __restrict__ plo,
    float* __restrict__ Gs) {
  const int pid = blockIdx.x >> 2, ks = blockIdx.x & 3;
  int bi = 0, rem = pid;
  while (rem >= 16 - bi) { rem -= 16 - bi; ++bi; }   // pid -> (bi, bj), bi<=bj
  const int bj = bi + rem;
  const bool diag = (bi == bj);
  __shared__ short As[2][64][64];            // [plane][row][k] bf16, part-swizzled
  __shared__ short Bs[2][64][64];
  const int t = threadIdx.x;
  const int w = t >> 6, l = t & 63;

  // staging roles: w0 A-hi, w1 A-lo, w2 B-hi, w3 B-lo; 8 instr each (8 rows/instr).
  // LDS dest linear: instr q, lane l -> row q*8+(l>>3), part l&7.
  // part p of row r holds global k-part (p ^ (r&7))  [pre-swizzled source]
  const unsigned short* plane = (w & 1) ? plo : phi;
  const int prow0 = (w & 2) ? bj * 64 : bi * 64;
  short* lbase = (w & 2) ? &Bs[w & 1][0][0] : &As[w & 1][0][0];
  const bool skipStage = diag && (w & 2);
  const unsigned short* gbase = plane
      + (size_t)(prow0 + (l >> 3)) * DCOLS + (((l & 7) ^ (l >> 3)) * 8);

  f32x4 acc[4] = {{0.f,0.f,0.f,0.f},{0.f,0.f,0.f,0.f},{0.f,0.f,0.f,0.f},{0.f,0.f,0.f,0.f}};
  double dacc[4][4] = {{0,0,0,0},{0,0,0,0},{0,0,0,0},{0,0,0,0}};

  const int arow = w * 16 + (l & 15);
  const int ar7  = arow & 7;
  const short* Bsrc0 = diag ? &As[0][0][0] : &Bs[0][0][0];
  const short* Bsrc1 = diag ? &As[1][0][0] : &Bs[1][0][0];
  const int kbeg = ks * 4096;

  for (int K0 = kbeg; K0 < kbeg + 4096; K0 += 2048) {
    for (int k0 = K0; k0 < K0 + 2048; k0 += 64) {
      __syncthreads();                        // previous chunk fully consumed
      if (!skipStage) {
        #pragma unroll
        for (int q = 0; q < 8; ++q)
          GLOAD_LDS16(gbase + (size_t)q * 8 * DCOLS + k0, lbase + q * 512);
      }
      __syncthreads();                        // staging drained
      const int p0 = ((l >> 4)) ^ ar7;
      const int p1 = (4 + (l >> 4)) ^ ar7;
      short8 ah0 = *(const short8*)&As[0][arow][p0 * 8];
      short8 ah1 = *(const short8*)&As[0][arow][p1 * 8];
      short8 al0 = *(const short8*)&As[1][arow][p0 * 8];
      short8 al1 = *(const short8*)&As[1][arow][p1 * 8];
      #pragma unroll
      for (int cj = 0; cj < 4; ++cj) {
        const int brow = cj * 16 + (l & 15);
        const int q0 = ((l >> 4)) ^ (brow & 7);
        const int q1 = (4 + (l >> 4)) ^ (brow & 7);
        short8 bh0 = *(const short8*)(Bsrc0 + brow * 64 + q0 * 8);
        short8 bh1 = *(const short8*)(Bsrc0 + brow * 64 + q1 * 8);
        short8 bl0 = *(const short8*)(Bsrc1 + brow * 64 + q0 * 8);
        short8 bl1 = *(const short8*)(Bsrc1 + brow * 64 + q1 * 8);
        acc[cj] = __builtin_amdgcn_mfma_f32_16x16x32_bf16(ah0, bh0, acc[cj], 0, 0, 0);
        acc[cj] = __builtin_amdgcn_mfma_f32_16x16x32_bf16(ah1, bh1, acc[cj], 0, 0, 0);
        acc[cj] = __builtin_amdgcn_mfma_f32_16x16x32_bf16(ah0, bl0, acc[cj], 0, 0, 0);
        acc[cj] = __builtin_amdgcn_mfma_f32_16x16x32_bf16(ah1, bl1, acc[cj], 0, 0, 0);
        acc[cj] = __builtin_amdgcn_mfma_f32_16x16x32_bf16(al0, bh0, acc[cj], 0, 0, 0);
        acc[cj] = __builtin_amdgcn_mfma_f32_16x16x32_bf16(al1, bh1, acc[cj], 0, 0, 0);
      }
    }
    #pragma unroll
    for (int cj = 0; cj < 4; ++cj) {          // fold every K=2048 (same cadence)
      #pragma unroll
      for (int v = 0; v < 4; ++v) dacc[cj][v] += (double)acc[cj][v];
      acc[cj] = (f32x4){0.f, 0.f, 0.f, 0.f};
    }
  }

  // write fp32 slice. C/D layout: col = lane&15, row = (lane>>4)*4 + v  [verified]
  float* gt = Gs + ((size_t)pid * 4 + ks) * 4096;
  #pragma unroll
  for (int cj = 0; cj < 4; ++cj)
    #pragma unroll
    for (int v = 0; v < 4; ++v)
      gt[(w * 16 + (l >> 4) * 4 + v) * 64 + cj * 16 + (l & 15)] = (float)dacc[cj][v];
}

// ---- K5e: per-pair epilogue — sum 4 slices (fp64), cov, both-direction |corr| partials ----
__global__ __launch_bounds__(256) void k_gepi(const float* __restrict__ Gs,
    const double* __restrict__ m, const double* __restrict__ dn,
    double* __restrict__ fpart) {
  const int pid = blockIdx.x;
  int bi = 0, rem = pid;
  while (rem >= 16 - bi) { rem -= 16 - bi; ++bi; }
  const int bj = bi + rem;
  const bool diag = (bi == bj);
  __shared__ double Gt[64][65];               // +1 pad: kills 16-way bank conflict
  const int t = threadIdx.x;
  const float* g = Gs + (size_t)pid * 4 * 4096;
  for (int i = t; i < 4096; i += 256) {
    double sg = ((double)g[i] + (double)g[4096 + i])
              + ((double)g[8192 + i] + (double)g[12288 + i]);   // fixed order: det.
    Gt[i >> 6][i & 63] = sg;
  }
  __syncthreads();
  // row-direction: thread t -> row r=t>>2, col quarter q=t&3 (16 cols)
  {
    const int r = t >> 2, q = t & 3;
    const double mi = m[bi * 64 + r] * 16384.0;
    double s = 0.0;
    #pragma unroll
    for (int i = 0; i < 16; ++i) {
      const int c = q * 16 + i;
      double cov = Gt[r][c] - mi * m[bj * 64 + c];
      s += fabs(cov) / dn[bj * 64 + c];
    }
    s += __shfl_xor(s, 1); s += __shfl_xor(s, 2);
    if (q == 0) fpart[(size_t)(bi * 64 + r) * 16 + bj] = s;
  }
  // col-direction (off-diag): thread t -> col c=t>>2, row quarter q=t&3
  if (!diag) {
    const int c = t >> 2, q = t & 3;
    const double mj = m[bj * 64 + c] * 16384.0;
    double sc = 0.0;
    #pragma unroll
    for (int i = 0; i < 16; ++i) {
      const int r = q * 16 + i;
      double cov = Gt[r][c] - m[bi * 64 + r] * mj;
      sc += fabs(cov) / dn[bi * 64 + r];
    }
    sc += __shfl_xor(sc, 1); sc += __shfl_xor(sc, 2);
    if (q == 0) fpart[(size_t)(bj * 64 + c) * 16 + bi] = sc;
  }
}

// ---- K5c: distributed self-check of fpart (both reduction directions), fp64 exact ----
__global__ __launch_bounds__(256) void k_check2(const float* __restrict__ x,
    const double* __restrict__ m, const double* __restrict__ dn,
    const double* __restrict__ fpart, float* __restrict__ flg) {
  const int b = blockIdx.x;
  const int t = threadIdx.x;
  __shared__ double red[64][4];
  __shared__ double terms[64];
  const int other = t & 63, kq = t >> 6;
  int r, cidx;
  if (b < 16) { r = b; cidx = 128 + other; }           // row r vs cols 128..191
  else        { r = 128 + (b - 16); cidx = other; }    // row j vs rows 0..63
  const float4* xa = (const float4*)(x + (size_t)r * DCOLS) + kq * 1024;
  const float4* xb = (const float4*)(x + (size_t)cidx * DCOLS) + kq * 1024;
  double g = 0.0;
  for (int k = 0; k < 1024; ++k) {
    float4 va = xa[k], vb = xb[k];
    g += (double)va.x * vb.x + (double)va.y * vb.y
       + (double)va.z * vb.z + (double)va.w * vb.w;
  }
  red[other][kq] = g;
  __syncthreads();
  if (t < 64) {
    double G = (red[t][0] + red[t][1]) + (red[t][2] + red[t][3]);
    int oc = (b < 16) ? (128 + t) : t;
    double cov = G - 16384.0 * m[r] * m[oc];
    terms[t] = fabs(cov) / dn[oc];
  }
  __syncthreads();
  if (t == 0) {
    double s = 0.0;
    for (int q = 0; q < 64; ++q) s += terms[q];
    double got = (b < 16) ? fpart[(size_t)r * 16 + 2] : fpart[(size_t)r * 16 + 0];
    if (fabs(got - s) > 2e-3 * fabs(s))
      atomicAdd(flg, (b < 16) ? 1e6f : 2e6f);
  }
}

// ---------------- K5b: fallback fp32-VALU Gram (small ws) ----------------
__global__ __launch_bounds__(256) void k_gram(const float* __restrict__ x,
    const double* __restrict__ m, const double* __restrict__ dn,
    double* __restrict__ fpart) {
  __shared__ float As[32][72];
  __shared__ float Bs[32][72];
  __shared__ double red[64][16];
  const int t = threadIdx.x;
  const int bi = blockIdx.y, bj = blockIdx.x;
  const int tx = t & 15, ty = t >> 4;
  const int lr = t >> 2, lc = t & 3;
  const float* Ap = x + (size_t)(bi * 64 + lr) * DCOLS;
  const float* Bp = x + (size_t)(bj * 64 + lr) * DCOLS;
  double acc[4][4];
  #pragma unroll
  for (int i = 0; i < 4; ++i)
    #pragma unroll
    for (int j = 0; j < 4; ++j) acc[i][j] = 0.0;
  float4 a0 = ((const float4*)Ap)[lc];
  float4 a1 = ((const float4*)Ap)[lc + 4];
  float4 b0 = ((const float4*)Bp)[lc];
  float4 b1 = ((const float4*)Bp)[lc + 4];
  for (int k0 = 0; k0 < DCOLS; k0 += 32) {
    __syncthreads();
    {
      const float* a0p = (const float*)&a0;
      const float* a1p = (const float*)&a1;
      const float* b0p = (const float*)&b0;
      const float* b1p = (const float*)&b1;
      #pragma unroll
      for (int jj = 0; jj < 4; ++jj) {
        As[lc * 4 + jj][lr]      = a0p[jj];
        As[16 + lc * 4 + jj][lr] = a1p[jj];
        Bs[lc * 4 + jj][lr]      = b0p[jj];
        Bs[16 + lc * 4 + jj][lr] = b1p[jj];
      }
    }
    __syncthreads();
    if (k0 + 32 < DCOLS) {
      a0 = ((const float4*)(Ap + k0 + 32))[lc];
      a1 = ((const float4*)(Ap + k0 + 32))[lc + 4];
      b0 = ((const float4*)(Bp + k0 + 32))[lc];
      b1 = ((const float4*)(Bp + k0 + 32))[lc + 4];
    }
    float ac[4][4];
    #pragma unroll
    for (int i = 0; i < 4; ++i)
      #pragma unroll
      for (int j = 0; j < 4; ++j) ac[i][j] = 0.0f;
    #pragma unroll
    for (int k = 0; k < 32; ++k) {
      const float4 av = *(const float4*)&As[k][ty * 4];
      const float4 bv = *(const float4*)&Bs[k][tx * 4];
      const float aa[4] = {av.x, av.y, av.z, av.w};
      const float bb[4] = {bv.x, bv.y, bv.z, bv.w};
      #pragma unroll
      for (int i = 0; i < 4; ++i)
        #pragma unroll
        for (int j = 0; j < 4; ++j)
          ac[i][j] += aa[i] * bb[j];
    }
    #pragma unroll
    for (int i = 0; i < 4; ++i)
      #pragma unroll
      for (int j = 0; j < 4; ++j) acc[i][j] += (double)ac[i][j];
  }
  double mr[4], mc[4], dc[4];
  #pragma unroll
  for (int i = 0; i < 4; ++i) mr[i] = m[bi * 64 + ty * 4 + i];
  #pragma unroll
  for (int j = 0; j < 4; ++j) {
    int col = bj * 64 + tx * 4 + j;
    mc[j] = m[col]; dc[j] = dn[col];
  }
  #pragma unroll
  for (int i = 0; i < 4; ++i) {
    double pi = 0.0;
    #pragma unroll
    for (int j = 0; j < 4; ++j) {
      double cov = acc[i][j] - 16384.0 * mr[i] * mc[j];
      pi += fabs(cov) / dc[j];
    }
    red[ty * 4 + i][tx] = pi;
  }
  __syncthreads();
  if (t < 64) {
    double ssum = 0.0;
    #pragma unroll
    for (int q = 0; q < 16; ++q) ssum += red[t][q];
    fpart[(size_t)(bi * 64 + t) * 16 + bj] = ssum;
  }
}

// ---------------- K3: per-row histogram (float32 np binning) + local entropy ----------------
__global__ __launch_bounds__(256) void k_hist(const float* __restrict__ x,
    const float* __restrict__ fscal, double* __restrict__ localent,
    unsigned* __restrict__ bc) {
#pragma clang fp contract(off)
  __shared__ unsigned h[BINS];
  const int row = blockIdx.x, t = threadIdx.x;
  for (int b = t; b < BINS; b += 256) h[b] = 0;
  __syncthreads();
  const float mu32 = fscal[0], sg32 = fscal[1], lof = fscal[2], wf = fscal[3];
  const float4* xr = (const float4*)(x + (size_t)row * DCOLS);
  for (int j = t; j < DCOLS / 4; j += 256) {
    float4 v = xr[j];
    float vv[4] = {v.x, v.y, v.z, v.w};
    #pragma unroll
    for (int c = 0; c < 4; ++c) {
      float tn = (vv[c] - mu32) / sg32;
      float q  = (tn - lof) / wf;
      int idx = (int)floorf(q);
      idx = idx < 0 ? 0 : (idx > BINS - 1 ? BINS - 1 : idx);
      atomicAdd(&h[idx], 1u);
    }
  }
  __syncthreads();
  const double Dw = (double)fscal[4];
  double ls = 0.0;
  for (int b = t; b < BINS; b += 256) {
    unsigned c = h[b];
    if (c) {
      atomicAdd(&bc[b], c);
      double pd = (double)c / Dw;
      ls -= pd * log2(pd);
    }
  }
  #pragma unroll
  for (int off = 32; off > 0; off >>= 1) ls += __shfl_down(ls, off);
  __shared__ double lsd[4];
  const int lane = t & 63, w = t >> 6;
  if (lane == 0) lsd[w] = ls;
  __syncthreads();
  if (t == 0) localent[row] = (lsd[0] + lsd[1]) + (lsd[2] + lsd[3]);
}

// ---------------- K4: batch entropy + per-row pf / keepf (float32 np chain) ----------------
__global__ __launch_bounds__(256) void k_final(const unsigned* __restrict__ bc,
    const float* __restrict__ fscal, const double* __restrict__ localent,
    const double* __restrict__ fpart, const double* __restrict__ dn,
    float* __restrict__ pf, float* __restrict__ kf) {
#pragma clang fp contract(off)
  const int t = threadIdx.x;
  const double Nw = (double)fscal[5];
  double be = 0.0;
  for (int b = t; b < BINS; b += 256) {
    unsigned c = bc[b];
    if (c) { double pd = (double)c / Nw; be -= pd * log2(pd); }
  }
  #pragma unroll
  for (int off = 32; off > 0; off >>= 1) be += __shfl_down(be, off);
  __shared__ double lsd[4];
  __shared__ double sbent;
  const int lane = t & 63, w = t >> 6;
  if (lane == 0) lsd[w] = be;
  __syncthreads();
  if (t == 0) sbent = (lsd[0] + lsd[1]) + (lsd[2] + lsd[3]);
  __syncthreads();
  const float bef = (float)sbent;
  for (int r = t; r < NROWS; r += 256) {
    double s = 0.0;
    #pragma unroll
    for (int q = 0; q < 16; ++q) s += fpart[(size_t)r * 16 + q];
    float f1f = (float)(s / (dn[r] * 1024.0));
    float lef = (float)localent[r];
    float f2f = lef / bef;
    if (f2f == 0.0f) { f1f = 0.0f; f2f = 1.0f; }
    else if (f2f < 1.0f) f2f = 1.0f / f2f;
    float keepf = f1f / f2f;
    pf[r] = 1.0f - keepf;
    kf[r] = keepf;
  }
}

// ---------------- K6: elementwise masked scale (float32 compare + division) ----------------
__global__ __launch_bounds__(256) void k_apply(const float* __restrict__ x,
    const float* __restrict__ u, const float* __restrict__ pf,
    const float* __restrict__ kf, const float* __restrict__ flg,
    float* __restrict__ out) {
#pragma clang fp contract(off)
  const size_t e = ((size_t)blockIdx.x * 256 + threadIdx.x) * 4;
  const float fl = flg[0];
  if (fl != 0.0f) {           // diagnostic mode: encode check code in out[0]
    float4 o = {0.f, 0.f, 0.f, 0.f};
    if (e == 0) o.x = fl;
    *(float4*)(out + e) = o;
    return;
  }
  const int row = (int)(e >> 14);
  const float pr = pf[row], kr = kf[row];
  const float4 xv = *(const float4*)(x + e);
  const float4 uv = *(const float4*)(u + e);
  float4 o;
  o.x = (uv.x > pr) ? (xv.x / kr) : 0.0f;
  o.y = (uv.y > pr) ? (xv.y / kr) : 0.0f;
  o.z = (uv.z > pr) ? (xv.z / kr) : 0.0f;
  o.w = (uv.w > pr) ? (xv.w / kr) : 0.0f;
  *(float4*)(out + e) = o;
}

extern "C" void kernel_launch(void* const* d_in, const int* in_sizes, int n_in,
                              void* d_out, int out_size, void* d_ws, size_t ws_size,
                              hipStream_t stream) {
  const float* x = (const float*)d_in[0];
  const float* u = (const float*)d_in[1];
  float* out = (float*)d_out;

  const size_t PLANE = (size_t)NROWS * DCOLS * sizeof(unsigned short);  // 32 MB
  const size_t NDBL  = 7 * 1024 + (size_t)NROWS * 16;                   // stats + fpart
  const size_t TAILB = NDBL * 8 + (2056 + 4) * 4 + BINS * 4;
  const bool big = ws_size >= 2 * PLANE + TAILB;

  char* base = (char*)d_ws;
  unsigned short* phi = (unsigned short*)base;
  unsigned short* plo = (unsigned short*)(base + PLANE);
  double* W = big ? (double*)(base + 2 * PLANE) : (double*)base;

  double* rowsum   = W;
  double* rowsumsq = W + 1024;
  double* rowmin   = W + 2048;
  double* rowmax   = W + 3072;
  double* m        = W + 4096;
  double* dn       = W + 5120;
  double* localent = W + 6144;
  double* fpart    = W + 7168;                        // 1024*16 doubles
  float*  F        = (float*)(W + 7168 + (size_t)NROWS * 16);
  float*  pf       = F;
  float*  kf       = F + 1024;
  float*  fscal    = F + 2048;          // 8 floats
  float*  flg      = F + 2056;          // 4 floats
  unsigned* bc     = (unsigned*)(F + 2060);

  if (big) {
    float* Gs = out;   // scratch: 136*4*4096 = 2.23M floats of the 16.7M out buffer
    k_rowsplit<<<NROWS, 256, 0, stream>>>(x, phi, plo, rowsum, rowsumsq, rowmin, rowmax);
    k_stats2<<<1, 256, 0, stream>>>(rowsum, rowsumsq, rowmin, rowmax, m, dn, fscal, flg, bc);
    k_gramm_sk<<<NPAIR * 4, 256, 0, stream>>>(phi, plo, Gs);
    k_gepi<<<NPAIR, 256, 0, stream>>>(Gs, m, dn, fpart);
    k_check2<<<80, 256, 0, stream>>>(x, m, dn, fpart, flg);
  } else {
    k_rowstats<<<NROWS, 256, 0, stream>>>(x, rowsum, rowsumsq, rowmin, rowmax);
    k_stats2<<<1, 256, 0, stream>>>(rowsum, rowsumsq, rowmin, rowmax, m, dn, fscal, flg, bc);
    k_gram<<<dim3(16, 16), 256, 0, stream>>>(x, m, dn, fpart);
  }
  k_hist<<<NROWS, 256, 0, stream>>>(x, fscal, localent, bc);
  k_final<<<1, 256, 0, stream>>>(bc, fscal, localent, fpart, dn, pf, kf);
  k_apply<<<NTOT / (256 * 4), 256, 0, stream>>>(x, u, pf, kf, flg, out);
}

// Round 10
// 213.465 us; speedup vs baseline: 7.4485x; 1.5435x over previous
//
#include <hip/hip_runtime.h>
#include <math.h>

#define NROWS 1024
#define DCOLS 16384
#define NTOT  16777216
#define BINS  1000
#define NPAIR 136   // 16*17/2 upper-triangle 64x64 tile pairs

typedef short short8 __attribute__((ext_vector_type(8)));
typedef unsigned short ushort8 __attribute__((ext_vector_type(8)));
typedef float f32x4 __attribute__((ext_vector_type(4)));

#define GLOAD_LDS16(gp, lp) __builtin_amdgcn_global_load_lds( \
    (const __attribute__((address_space(1))) unsigned int*)(gp), \
    (__attribute__((address_space(3))) unsigned int*)(lp), 16, 0, 0)

// check-entry tables: target row, col base, fpart slot
__device__ __constant__ int CHK_TR[12] = {1,17,33,49,  0,5,10,15,  128,149,170,191};
__device__ __constant__ int CHK_CB[12] = {0,0,0,0,     128,128,128,128,  0,0,0,0};
__device__ __constant__ int CHK_SL[12] = {0,0,0,0,     2,2,2,2,    0,0,0,0};

// ---------------- K0: fused per-row stats + bf16 hi/lo split (one x pass) ----------------
__global__ __launch_bounds__(256) void k_rowsplit(const float* __restrict__ x,
    unsigned short* __restrict__ phi, unsigned short* __restrict__ plo,
    double* __restrict__ rowsum, double* __restrict__ rowsumsq,
    double* __restrict__ rowmin, double* __restrict__ rowmax) {
  const int row = blockIdx.x, t = threadIdx.x;
  const size_t base = (size_t)row * DCOLS;
  double s = 0.0, s2 = 0.0;
  float mn = 3.4028235e38f, mx = -3.4028235e38f;
  #pragma unroll
  for (int i = 0; i < 8; ++i) {
    const size_t off = base + (size_t)i * 2048 + (size_t)t * 8;
    const float4 v0 = *(const float4*)(x + off);
    const float4 v1 = *(const float4*)(x + off + 4);
    const float vv[8] = {v0.x, v0.y, v0.z, v0.w, v1.x, v1.y, v1.z, v1.w};
    ushort8 h, lo;
    #pragma unroll
    for (int c = 0; c < 8; ++c) {
      unsigned ub = __float_as_uint(vv[c]);
      unsigned hb = (ub + 0x7FFFu + ((ub >> 16) & 1u)) >> 16;   // RNE bf16
      float hf = __uint_as_float(hb << 16);
      float r = vv[c] - hf;                                      // exact
      unsigned ur = __float_as_uint(r);
      unsigned lb = (ur + 0x7FFFu + ((ur >> 16) & 1u)) >> 16;   // RNE bf16
      h[c] = (unsigned short)hb; lo[c] = (unsigned short)lb;
      double dv = vv[c];
      s += dv; s2 += dv * dv;
      mn = fminf(mn, vv[c]); mx = fmaxf(mx, vv[c]);
    }
    *(ushort8*)(phi + off) = h;
    *(ushort8*)(plo + off) = lo;
  }
  #pragma unroll
  for (int off = 32; off > 0; off >>= 1) {
    s  += __shfl_down(s, off);
    s2 += __shfl_down(s2, off);
    mn = fminf(mn, __shfl_down(mn, off));
    mx = fmaxf(mx, __shfl_down(mx, off));
  }
  __shared__ double lsd[8];
  __shared__ float  lsf[8];
  const int lane = t & 63, w = t >> 6;
  if (lane == 0) { lsd[w] = s; lsd[4 + w] = s2; lsf[w] = mn; lsf[4 + w] = mx; }
  __syncthreads();
  if (t == 0) {
    rowsum[row]   = (lsd[0] + lsd[1]) + (lsd[2] + lsd[3]);
    rowsumsq[row] = (lsd[4] + lsd[5]) + (lsd[6] + lsd[7]);
    rowmin[row] = (double)fminf(fminf(lsf[0], lsf[1]), fminf(lsf[2], lsf[3]));
    rowmax[row] = (double)fmaxf(fmaxf(lsf[4], lsf[5]), fmaxf(lsf[6], lsf[7]));
  }
}

// ---------------- K1 (fallback path only): per-row stats without split ----------------
__global__ __launch_bounds__(256) void k_rowstats(const float* __restrict__ x,
    double* __restrict__ rowsum, double* __restrict__ rowsumsq,
    double* __restrict__ rowmin, double* __restrict__ rowmax) {
  const int row = blockIdx.x;
  const int t = threadIdx.x;
  const float4* xr = (const float4*)(x + (size_t)row * DCOLS);
  double s = 0.0, s2 = 0.0;
  float mn = 3.4028235e38f, mx = -3.4028235e38f;
  for (int j = t; j < DCOLS / 4; j += 256) {
    float4 v = xr[j];
    double a = v.x, b = v.y, c = v.z, d = v.w;
    s  += (a + b) + (c + d);
    s2 += (a * a + b * b) + (c * c + d * d);
    mn = fminf(mn, fminf(fminf(v.x, v.y), fminf(v.z, v.w)));
    mx = fmaxf(mx, fmaxf(fmaxf(v.x, v.y), fmaxf(v.z, v.w)));
  }
  #pragma unroll
  for (int off = 32; off > 0; off >>= 1) {
    s  += __shfl_down(s, off);
    s2 += __shfl_down(s2, off);
    mn = fminf(mn, __shfl_down(mn, off));
    mx = fmaxf(mx, __shfl_down(mx, off));
  }
  __shared__ double lsd[8];
  __shared__ float  lsf[8];
  const int lane = t & 63, w = t >> 6;
  if (lane == 0) { lsd[w] = s; lsd[4 + w] = s2; lsf[w] = mn; lsf[4 + w] = mx; }
  __syncthreads();
  if (t == 0) {
    rowsum[row]   = (lsd[0] + lsd[1]) + (lsd[2] + lsd[3]);
    rowsumsq[row] = (lsd[4] + lsd[5]) + (lsd[6] + lsd[7]);
    rowmin[row] = (double)fminf(fminf(lsf[0], lsf[1]), fminf(lsf[2], lsf[3]));
    rowmax[row] = (double)fmaxf(fmaxf(lsf[4], lsf[5]), fmaxf(lsf[6], lsf[7]));
  }
}

// ---------------- K2: global scalars (fp64 stats -> float32 np-style scalars) + bc zero ----------------
__global__ __launch_bounds__(256) void k_stats2(
    const double* __restrict__ rowsum, const double* __restrict__ rowsumsq,
    const double* __restrict__ rowmin, const double* __restrict__ rowmax,
    double* __restrict__ m, double* __restrict__ dn, float* __restrict__ fscal,
    float* __restrict__ flg, unsigned* __restrict__ bc) {
#pragma clang fp contract(off)
  const int t = threadIdx.x;
  for (int b = t; b < BINS; b += 256) bc[b] = 0;
  double s = 0.0, s2 = 0.0, mn = 1e300, mx = -1e300;
  for (int r = t; r < NROWS; r += 256) {
    s += rowsum[r]; s2 += rowsumsq[r];
    mn = fmin(mn, rowmin[r]); mx = fmax(mx, rowmax[r]);
  }
  #pragma unroll
  for (int off = 32; off > 0; off >>= 1) {
    s  += __shfl_down(s, off);
    s2 += __shfl_down(s2, off);
    mn = fmin(mn, __shfl_down(mn, off));
    mx = fmax(mx, __shfl_down(mx, off));
  }
  __shared__ double lsd[16];
  const int lane = t & 63, w = t >> 6;
  if (lane == 0) { lsd[w] = s; lsd[4 + w] = s2; lsd[8 + w] = mn; lsd[12 + w] = mx; }
  __syncthreads();
  if (t == 0) {
    double S  = (lsd[0] + lsd[1]) + (lsd[2] + lsd[3]);
    double S2 = (lsd[4] + lsd[5]) + (lsd[6] + lsd[7]);
    double MN = fmin(fmin(lsd[8], lsd[9]), fmin(lsd[10], lsd[11]));
    double MX = fmax(fmax(lsd[12], lsd[13]), fmax(lsd[14], lsd[15]));
    const double N = 16777216.0;
    double mu  = S / N;
    double var = (S2 - S * S / N) / (N - 1.0);
    double sig = sqrt(var);
    float mu32 = (float)mu;
    float sg32 = (float)sig;
    float mnf  = (float)MN;
    float mxf  = (float)MX;
    float lof  = (mnf - mu32) / sg32;
    float hif  = (mxf - mu32) / sg32;
    float wf   = (hif - lof) / 1000.0f;
    fscal[0] = mu32;
    fscal[1] = sg32;
    fscal[2] = lof;
    fscal[3] = wf;
    fscal[4] = 16384.0f * wf;
    fscal[5] = 16777216.0f * wf;
    flg[0] = 0.0f;
  }
  __syncthreads();
  for (int r = t; r < NROWS; r += 256) {
    double rs = rowsum[r];
    m[r]  = rs / 16384.0;
    dn[r] = sqrt(rowsumsq[r] - rs * rs * (1.0 / 16384.0));
  }
}

// ---- K5a: split-K MFMA Gram. 544 blocks = 136 pairs x 4 K-quarters (K=4096 each).
__global__ __launch_bounds__(256) void k_gramm_sk(
    const unsigned short* __restrict__ phi, const unsigned short* __restrict__ plo,
    float* __restrict__ Gs) {
  const int pid = blockIdx.x >> 2, ks = blockIdx.x & 3;
  int bi = 0, rem = pid;
  while (rem >= 16 - bi) { rem -= 16 - bi; ++bi; }   // pid -> (bi, bj), bi<=bj
  const int bj = bi + rem;
  const bool diag = (bi == bj);
  __shared__ short As[2][64][64];            // [plane][row][k] bf16, part-swizzled
  __shared__ short Bs[2][64][64];
  const int t = threadIdx.x;
  const int w = t >> 6, l = t & 63;

  const unsigned short* plane = (w & 1) ? plo : phi;
  const int prow0 = (w & 2) ? bj * 64 : bi * 64;
  short* lbase = (w & 2) ? &Bs[w & 1][0][0] : &As[w & 1][0][0];
  const bool skipStage = diag && (w & 2);
  const unsigned short* gbase = plane
      + (size_t)(prow0 + (l >> 3)) * DCOLS + (((l & 7) ^ (l >> 3)) * 8);

  f32x4 acc[4] = {{0.f,0.f,0.f,0.f},{0.f,0.f,0.f,0.f},{0.f,0.f,0.f,0.f},{0.f,0.f,0.f,0.f}};
  double dacc[4][4] = {{0,0,0,0},{0,0,0,0},{0,0,0,0},{0,0,0,0}};

  const int arow = w * 16 + (l & 15);
  const int ar7  = arow & 7;
  const short* Bsrc0 = diag ? &As[0][0][0] : &Bs[0][0][0];
  const short* Bsrc1 = diag ? &As[1][0][0] : &Bs[1][0][0];
  const int kbeg = ks * 4096;

  for (int K0 = kbeg; K0 < kbeg + 4096; K0 += 2048) {
    for (int k0 = K0; k0 < K0 + 2048; k0 += 64) {
      __syncthreads();                        // previous chunk fully consumed
      if (!skipStage) {
        #pragma unroll
        for (int q = 0; q < 8; ++q)
          GLOAD_LDS16(gbase + (size_t)q * 8 * DCOLS + k0, lbase + q * 512);
      }
      __syncthreads();                        // staging drained
      const int p0 = ((l >> 4)) ^ ar7;
      const int p1 = (4 + (l >> 4)) ^ ar7;
      short8 ah0 = *(const short8*)&As[0][arow][p0 * 8];
      short8 ah1 = *(const short8*)&As[0][arow][p1 * 8];
      short8 al0 = *(const short8*)&As[1][arow][p0 * 8];
      short8 al1 = *(const short8*)&As[1][arow][p1 * 8];
      #pragma unroll
      for (int cj = 0; cj < 4; ++cj) {
        const int brow = cj * 16 + (l & 15);
        const int q0 = ((l >> 4)) ^ (brow & 7);
        const int q1 = (4 + (l >> 4)) ^ (brow & 7);
        short8 bh0 = *(const short8*)(Bsrc0 + brow * 64 + q0 * 8);
        short8 bh1 = *(const short8*)(Bsrc0 + brow * 64 + q1 * 8);
        short8 bl0 = *(const short8*)(Bsrc1 + brow * 64 + q0 * 8);
        short8 bl1 = *(const short8*)(Bsrc1 + brow * 64 + q1 * 8);
        acc[cj] = __builtin_amdgcn_mfma_f32_16x16x32_bf16(ah0, bh0, acc[cj], 0, 0, 0);
        acc[cj] = __builtin_amdgcn_mfma_f32_16x16x32_bf16(ah1, bh1, acc[cj], 0, 0, 0);
        acc[cj] = __builtin_amdgcn_mfma_f32_16x16x32_bf16(ah0, bl0, acc[cj], 0, 0, 0);
        acc[cj] = __builtin_amdgcn_mfma_f32_16x16x32_bf16(ah1, bl1, acc[cj], 0, 0, 0);
        acc[cj] = __builtin_amdgcn_mfma_f32_16x16x32_bf16(al0, bh0, acc[cj], 0, 0, 0);
        acc[cj] = __builtin_amdgcn_mfma_f32_16x16x32_bf16(al1, bh1, acc[cj], 0, 0, 0);
      }
    }
    #pragma unroll
    for (int cj = 0; cj < 4; ++cj) {          // fold every K=2048
      #pragma unroll
      for (int v = 0; v < 4; ++v) dacc[cj][v] += (double)acc[cj][v];
      acc[cj] = (f32x4){0.f, 0.f, 0.f, 0.f};
    }
  }

  // write fp32 slice. C/D layout: col = lane&15, row = (lane>>4)*4 + v  [verified]
  float* gt = Gs + ((size_t)pid * 4 + ks) * 4096;
  #pragma unroll
  for (int cj = 0; cj < 4; ++cj)
    #pragma unroll
    for (int v = 0; v < 4; ++v)
      gt[(w * 16 + (l >> 4) * 4 + v) * 64 + cj * 16 + (l & 15)] = (float)dacc[cj][v];
}

// ---- K5e: per-pair epilogue — sum 4 slices (fp64), cov, both-direction |corr| partials ----
__global__ __launch_bounds__(256) void k_gepi(const float* __restrict__ Gs,
    const double* __restrict__ m, const double* __restrict__ dn,
    double* __restrict__ fpart) {
  const int pid = blockIdx.x;
  int bi = 0, rem = pid;
  while (rem >= 16 - bi) { rem -= 16 - bi; ++bi; }
  const int bj = bi + rem;
  const bool diag = (bi == bj);
  __shared__ double Gt[64][65];               // +1 pad: kills bank conflict
  const int t = threadIdx.x;
  const float* g = Gs + (size_t)pid * 4 * 4096;
  for (int i = t; i < 4096; i += 256) {
    double sg = ((double)g[i] + (double)g[4096 + i])
              + ((double)g[8192 + i] + (double)g[12288 + i]);   // fixed order: det.
    Gt[i >> 6][i & 63] = sg;
  }
  __syncthreads();
  // row-direction: thread t -> row r=t>>2, col quarter q=t&3 (16 cols)
  {
    const int r = t >> 2, q = t & 3;
    const double mi = m[bi * 64 + r] * 16384.0;
    double s = 0.0;
    #pragma unroll
    for (int i = 0; i < 16; ++i) {
      const int c = q * 16 + i;
      double cov = Gt[r][c] - mi * m[bj * 64 + c];
      s += fabs(cov) / dn[bj * 64 + c];
    }
    s += __shfl_xor(s, 1); s += __shfl_xor(s, 2);
    if (q == 0) fpart[(size_t)(bi * 64 + r) * 16 + bj] = s;
  }
  // col-direction (off-diag): thread t -> col c=t>>2, row quarter q=t&3
  if (!diag) {
    const int c = t >> 2, q = t & 3;
    const double mj = m[bj * 64 + c] * 16384.0;
    double sc = 0.0;
    #pragma unroll
    for (int i = 0; i < 16; ++i) {
      const int r = q * 16 + i;
      double cov = Gt[r][c] - m[bi * 64 + r] * mj;
      sc += fabs(cov) / dn[bi * 64 + r];
    }
    sc += __shfl_xor(sc, 1); sc += __shfl_xor(sc, 2);
    if (q == 0) fpart[(size_t)(bj * 64 + c) * 16 + bi] = sc;
  }
}

// ---- K5c: cheap distributed spot-check — 12 fpart entries, fp64 exact, 96 blocks ----
// block = entry e (12) x col-group grp (8).  256 thr = 8 cols x 32 k-segments.
// chkpart[e*8+grp] = partial sum of 8 |cov|/dn terms; compared in k_final.
__global__ __launch_bounds__(256) void k_check3(const float* __restrict__ x,
    const double* __restrict__ m, const double* __restrict__ dn,
    double* __restrict__ chkpart) {
  const int b = blockIdx.x;
  const int e = b >> 3, grp = b & 7;
  const int t = threadIdx.x;
  const int cl = t >> 5;            // 0..7: col within group
  const int ks = t & 31;            // 0..31: k segment (512 elems)
  const int trow = CHK_TR[e];
  const int col  = CHK_CB[e] + grp * 8 + cl;
  const float4* xa = (const float4*)(x + (size_t)trow * DCOLS) + ks * 128;
  const float4* xb = (const float4*)(x + (size_t)col  * DCOLS) + ks * 128;
  double g = 0.0;
  for (int k = 0; k < 128; ++k) {
    float4 va = xa[k], vb = xb[k];
    g += (double)va.x * vb.x + (double)va.y * vb.y
       + (double)va.z * vb.z + (double)va.w * vb.w;
  }
  // reduce over 32 k-segments (xor masks 1..16 stay within the 32-lane group)
  g += __shfl_xor(g, 1); g += __shfl_xor(g, 2); g += __shfl_xor(g, 4);
  g += __shfl_xor(g, 8); g += __shfl_xor(g, 16);
  __shared__ double cd[8];
  if (ks == 0) cd[cl] = g;
  __syncthreads();
  if (t == 0) {
    double s = 0.0;
    #pragma unroll
    for (int i = 0; i < 8; ++i) {
      int c = CHK_CB[e] + grp * 8 + i;
      double cov = cd[i] - 16384.0 * m[trow] * m[c];
      s += fabs(cov) / dn[c];
    }
    chkpart[e * 8 + grp] = s;
  }
}

// ---------------- K5b: fallback fp32-VALU Gram (small ws) ----------------
__global__ __launch_bounds__(256) void k_gram(const float* __restrict__ x,
    const double* __restrict__ m, const double* __restrict__ dn,
    double* __restrict__ fpart) {
  __shared__ float As[32][72];
  __shared__ float Bs[32][72];
  __shared__ double red[64][16];
  const int t = threadIdx.x;
  const int bi = blockIdx.y, bj = blockIdx.x;
  const int tx = t & 15, ty = t >> 4;
  const int lr = t >> 2, lc = t & 3;
  const float* Ap = x + (size_t)(bi * 64 + lr) * DCOLS;
  const float* Bp = x + (size_t)(bj * 64 + lr) * DCOLS;
  double acc[4][4];
  #pragma unroll
  for (int i = 0; i < 4; ++i)
    #pragma unroll
    for (int j = 0; j < 4; ++j) acc[i][j] = 0.0;
  float4 a0 = ((const float4*)Ap)[lc];
  float4 a1 = ((const float4*)Ap)[lc + 4];
  float4 b0 = ((const float4*)Bp)[lc];
  float4 b1 = ((const float4*)Bp)[lc + 4];
  for (int k0 = 0; k0 < DCOLS; k0 += 32) {
    __syncthreads();
    {
      const float* a0p = (const float*)&a0;
      const float* a1p = (const float*)&a1;
      const float* b0p = (const float*)&b0;
      const float* b1p = (const float*)&b1;
      #pragma unroll
      for (int jj = 0; jj < 4; ++jj) {
        As[lc * 4 + jj][lr]      = a0p[jj];
        As[16 + lc * 4 + jj][lr] = a1p[jj];
        Bs[lc * 4 + jj][lr]      = b0p[jj];
        Bs[16 + lc * 4 + jj][lr] = b1p[jj];
      }
    }
    __syncthreads();
    if (k0 + 32 < DCOLS) {
      a0 = ((const float4*)(Ap + k0 + 32))[lc];
      a1 = ((const float4*)(Ap + k0 + 32))[lc + 4];
      b0 = ((const float4*)(Bp + k0 + 32))[lc];
      b1 = ((const float4*)(Bp + k0 + 32))[lc + 4];
    }
    float ac[4][4];
    #pragma unroll
    for (int i = 0; i < 4; ++i)
      #pragma unroll
      for (int j = 0; j < 4; ++j) ac[i][j] = 0.0f;
    #pragma unroll
    for (int k = 0; k < 32; ++k) {
      const float4 av = *(const float4*)&As[k][ty * 4];
      const float4 bv = *(const float4*)&Bs[k][tx * 4];
      const float aa[4] = {av.x, av.y, av.z, av.w};
      const float bb[4] = {bv.x, bv.y, bv.z, bv.w};
      #pragma unroll
      for (int i = 0; i < 4; ++i)
        #pragma unroll
        for (int j = 0; j < 4; ++j)
          ac[i][j] += aa[i] * bb[j];
    }
    #pragma unroll
    for (int i = 0; i < 4; ++i)
      #pragma unroll
      for (int j = 0; j < 4; ++j) acc[i][j] += (double)ac[i][j];
  }
  double mr[4], mc[4], dc[4];
  #pragma unroll
  for (int i = 0; i < 4; ++i) mr[i] = m[bi * 64 + ty * 4 + i];
  #pragma unroll
  for (int j = 0; j < 4; ++j) {
    int col = bj * 64 + tx * 4 + j;
    mc[j] = m[col]; dc[j] = dn[col];
  }
  #pragma unroll
  for (int i = 0; i < 4; ++i) {
    double pi = 0.0;
    #pragma unroll
    for (int j = 0; j < 4; ++j) {
      double cov = acc[i][j] - 16384.0 * mr[i] * mc[j];
      pi += fabs(cov) / dc[j];
    }
    red[ty * 4 + i][tx] = pi;
  }
  __syncthreads();
  if (t < 64) {
    double ssum = 0.0;
    #pragma unroll
    for (int q = 0; q < 16; ++q) ssum += red[t][q];
    fpart[(size_t)(bi * 64 + t) * 16 + bj] = ssum;
  }
}

// ---------------- K3: per-row histogram (float32 np binning) + local entropy ----------------
__global__ __launch_bounds__(256) void k_hist(const float* __restrict__ x,
    const float* __restrict__ fscal, double* __restrict__ localent,
    unsigned* __restrict__ bc) {
#pragma clang fp contract(off)
  __shared__ unsigned h[BINS];
  const int row = blockIdx.x, t = threadIdx.x;
  for (int b = t; b < BINS; b += 256) h[b] = 0;
  __syncthreads();
  const float mu32 = fscal[0], sg32 = fscal[1], lof = fscal[2], wf = fscal[3];
  const float4* xr = (const float4*)(x + (size_t)row * DCOLS);
  for (int j = t; j < DCOLS / 4; j += 256) {
    float4 v = xr[j];
    float vv[4] = {v.x, v.y, v.z, v.w};
    #pragma unroll
    for (int c = 0; c < 4; ++c) {
      float tn = (vv[c] - mu32) / sg32;
      float q  = (tn - lof) / wf;
      int idx = (int)floorf(q);
      idx = idx < 0 ? 0 : (idx > BINS - 1 ? BINS - 1 : idx);
      atomicAdd(&h[idx], 1u);
    }
  }
  __syncthreads();
  const double Dw = (double)fscal[4];
  double ls = 0.0;
  for (int b = t; b < BINS; b += 256) {
    unsigned c = h[b];
    if (c) {
      atomicAdd(&bc[b], c);
      double pd = (double)c / Dw;
      ls -= pd * log2(pd);
    }
  }
  #pragma unroll
  for (int off = 32; off > 0; off >>= 1) ls += __shfl_down(ls, off);
  __shared__ double lsd[4];
  const int lane = t & 63, w = t >> 6;
  if (lane == 0) lsd[w] = ls;
  __syncthreads();
  if (t == 0) localent[row] = (lsd[0] + lsd[1]) + (lsd[2] + lsd[3]);
}

// ---------------- K4: batch entropy + per-row pf/keepf + fpart spot-check compare ----------------
__global__ __launch_bounds__(256) void k_final(const unsigned* __restrict__ bc,
    const float* __restrict__ fscal, const double* __restrict__ localent,
    const double* __restrict__ fpart, const double* __restrict__ dn,
    const double* __restrict__ chkpart, float* __restrict__ flg,
    float* __restrict__ pf, float* __restrict__ kf) {
#pragma clang fp contract(off)
  const int t = threadIdx.x;
  if (t < 12) {    // compare spot-check entries vs fpart (flg consumed later by k_apply)
    double s = 0.0;
    #pragma unroll
    for (int q = 0; q < 8; ++q) s += chkpart[t * 8 + q];
    double got = fpart[(size_t)CHK_TR[t] * 16 + CHK_SL[t]];
    if (fabs(got - s) > 2e-3 * fmax(fabs(s), 1e-30))
      atomicAdd(flg, 1e6f * (float)(t + 1));
  }
  const double Nw = (double)fscal[5];
  double be = 0.0;
  for (int b = t; b < BINS; b += 256) {
    unsigned c = bc[b];
    if (c) { double pd = (double)c / Nw; be -= pd * log2(pd); }
  }
  #pragma unroll
  for (int off = 32; off > 0; off >>= 1) be += __shfl_down(be, off);
  __shared__ double lsd[4];
  __shared__ double sbent;
  const int lane = t & 63, w = t >> 6;
  if (lane == 0) lsd[w] = be;
  __syncthreads();
  if (t == 0) sbent = (lsd[0] + lsd[1]) + (lsd[2] + lsd[3]);
  __syncthreads();
  const float bef = (float)sbent;
  for (int r = t; r < NROWS; r += 256) {
    double s = 0.0;
    #pragma unroll
    for (int q = 0; q < 16; ++q) s += fpart[(size_t)r * 16 + q];
    float f1f = (float)(s / (dn[r] * 1024.0));
    float lef = (float)localent[r];
    float f2f = lef / bef;
    if (f2f == 0.0f) { f1f = 0.0f; f2f = 1.0f; }
    else if (f2f < 1.0f) f2f = 1.0f / f2f;
    float keepf = f1f / f2f;
    pf[r] = 1.0f - keepf;
    kf[r] = keepf;
  }
}

// ---------------- K6: elementwise masked scale (float32 compare + division) ----------------
__global__ __launch_bounds__(256) void k_apply(const float* __restrict__ x,
    const float* __restrict__ u, const float* __restrict__ pf,
    const float* __restrict__ kf, const float* __restrict__ flg,
    float* __restrict__ out) {
#pragma clang fp contract(off)
  const size_t e = ((size_t)blockIdx.x * 256 + threadIdx.x) * 4;
  const float fl = flg[0];
  if (fl != 0.0f) {           // diagnostic mode: encode check code in out[0]
    float4 o = {0.f, 0.f, 0.f, 0.f};
    if (e == 0) o.x = fl;
    *(float4*)(out + e) = o;
    return;
  }
  const int row = (int)(e >> 14);
  const float pr = pf[row], kr = kf[row];
  const float4 xv = *(const float4*)(x + e);
  const float4 uv = *(const float4*)(u + e);
  float4 o;
  o.x = (uv.x > pr) ? (xv.x / kr) : 0.0f;
  o.y = (uv.y > pr) ? (xv.y / kr) : 0.0f;
  o.z = (uv.z > pr) ? (xv.z / kr) : 0.0f;
  o.w = (uv.w > pr) ? (xv.w / kr) : 0.0f;
  *(float4*)(out + e) = o;
}

extern "C" void kernel_launch(void* const* d_in, const int* in_sizes, int n_in,
                              void* d_out, int out_size, void* d_ws, size_t ws_size,
                              hipStream_t stream) {
  const float* x = (const float*)d_in[0];
  const float* u = (const float*)d_in[1];
  float* out = (float*)d_out;

  const size_t PLANE = (size_t)NROWS * DCOLS * sizeof(unsigned short);  // 32 MB
  const size_t NDBL  = 7 * 1024 + (size_t)NROWS * 16 + 96;              // stats + fpart + chkpart
  const size_t TAILB = NDBL * 8 + (2056 + 4) * 4 + BINS * 4;
  const bool big = ws_size >= 2 * PLANE + TAILB;

  char* base = (char*)d_ws;
  unsigned short* phi = (unsigned short*)base;
  unsigned short* plo = (unsigned short*)(base + PLANE);
  double* W = big ? (double*)(base + 2 * PLANE) : (double*)base;

  double* rowsum   = W;
  double* rowsumsq = W + 1024;
  double* rowmin   = W + 2048;
  double* rowmax   = W + 3072;
  double* m        = W + 4096;
  double* dn       = W + 5120;
  double* localent = W + 6144;
  double* fpart    = W + 7168;                        // 1024*16 doubles
  double* chkpart  = W + 7168 + (size_t)NROWS * 16;   // 96 doubles
  float*  F        = (float*)(chkpart + 96);
  float*  pf       = F;
  float*  kf       = F + 1024;
  float*  fscal    = F + 2048;          // 8 floats
  float*  flg      = F + 2056;          // 4 floats
  unsigned* bc     = (unsigned*)(F + 2060);

  if (big) {
    float* Gs = out;   // scratch: 136*4*4096 = 2.23M floats of the 16.7M out buffer
    k_rowsplit<<<NROWS, 256, 0, stream>>>(x, phi, plo, rowsum, rowsumsq, rowmin, rowmax);
    k_stats2<<<1, 256, 0, stream>>>(rowsum, rowsumsq, rowmin, rowmax, m, dn, fscal, flg, bc);
    k_gramm_sk<<<NPAIR * 4, 256, 0, stream>>>(phi, plo, Gs);
    k_gepi<<<NPAIR, 256, 0, stream>>>(Gs, m, dn, fpart);
    k_check3<<<96, 256, 0, stream>>>(x, m, dn, chkpart);
  } else {
    k_rowstats<<<NROWS, 256, 0, stream>>>(x, rowsum, rowsumsq, rowmin, rowmax);
    k_stats2<<<1, 256, 0, stream>>>(rowsum, rowsumsq, rowmin, rowmax, m, dn, fscal, flg, bc);
    k_gram<<<dim3(16, 16), 256, 0, stream>>>(x, m, dn, fpart);
    // fallback: zero chkpart so k_final's compare sees consistent values? fallback writes
    // fpart only 16 slots; spot-check invalid -> fill chkpart from fpart to force match:
    // simplest: skip compare by writing matching values is complex; instead run k_check3 too.
    k_check3<<<96, 256, 0, stream>>>(x, m, dn, chkpart);
  }
  k_hist<<<NROWS, 256, 0, stream>>>(x, fscal, localent, bc);
  k_final<<<1, 256, 0, stream>>>(bc, fscal, localent, fpart, dn, chkpart, flg, pf, kf);
  k_apply<<<NTOT / (256 * 4), 256, 0, stream>>>(x, u, pf, kf, flg, out);
}

// Round 11
// 203.009 us; speedup vs baseline: 7.8322x; 1.0515x over previous
//
#include <hip/hip_runtime.h>
#include <math.h>

#define NROWS 1024
#define DCOLS 16384
#define NTOT  16777216
#define BINS  1000
#define NPAIR 136   // 16*17/2 upper-triangle 64x64 tile pairs
#define KSPL  8     // split-K ways

typedef short short8 __attribute__((ext_vector_type(8)));
typedef unsigned short ushort8 __attribute__((ext_vector_type(8)));
typedef float f32x4 __attribute__((ext_vector_type(4)));

#define GLOAD_LDS16(gp, lp) __builtin_amdgcn_global_load_lds( \
    (const __attribute__((address_space(1))) unsigned int*)(gp), \
    (__attribute__((address_space(3))) unsigned int*)(lp), 16, 0, 0)

// check-entry tables: target row, col base, fpart slot
__device__ __constant__ int CHK_TR[12] = {1,17,33,49,  0,5,10,15,  128,149,170,191};
__device__ __constant__ int CHK_CB[12] = {0,0,0,0,     128,128,128,128,  0,0,0,0};
__device__ __constant__ int CHK_SL[12] = {0,0,0,0,     2,2,2,2,    0,0,0,0};

// ---------------- K0: fused per-row stats + bf16 hi/lo split (one x pass) ----------------
__global__ __launch_bounds__(256) void k_rowsplit(const float* __restrict__ x,
    unsigned short* __restrict__ phi, unsigned short* __restrict__ plo,
    double* __restrict__ rowsum, double* __restrict__ rowsumsq,
    double* __restrict__ rowmin, double* __restrict__ rowmax) {
  const int row = blockIdx.x, t = threadIdx.x;
  const size_t base = (size_t)row * DCOLS;
  double s = 0.0, s2 = 0.0;
  float mn = 3.4028235e38f, mx = -3.4028235e38f;
  #pragma unroll
  for (int i = 0; i < 8; ++i) {
    const size_t off = base + (size_t)i * 2048 + (size_t)t * 8;
    const float4 v0 = *(const float4*)(x + off);
    const float4 v1 = *(const float4*)(x + off + 4);
    const float vv[8] = {v0.x, v0.y, v0.z, v0.w, v1.x, v1.y, v1.z, v1.w};
    ushort8 h, lo;
    #pragma unroll
    for (int c = 0; c < 8; ++c) {
      unsigned ub = __float_as_uint(vv[c]);
      unsigned hb = (ub + 0x7FFFu + ((ub >> 16) & 1u)) >> 16;   // RNE bf16
      float hf = __uint_as_float(hb << 16);
      float r = vv[c] - hf;                                      // exact
      unsigned ur = __float_as_uint(r);
      unsigned lb = (ur + 0x7FFFu + ((ur >> 16) & 1u)) >> 16;   // RNE bf16
      h[c] = (unsigned short)hb; lo[c] = (unsigned short)lb;
      double dv = vv[c];
      s += dv; s2 += dv * dv;
      mn = fminf(mn, vv[c]); mx = fmaxf(mx, vv[c]);
    }
    *(ushort8*)(phi + off) = h;
    *(ushort8*)(plo + off) = lo;
  }
  #pragma unroll
  for (int off = 32; off > 0; off >>= 1) {
    s  += __shfl_down(s, off);
    s2 += __shfl_down(s2, off);
    mn = fminf(mn, __shfl_down(mn, off));
    mx = fmaxf(mx, __shfl_down(mx, off));
  }
  __shared__ double lsd[8];
  __shared__ float  lsf[8];
  const int lane = t & 63, w = t >> 6;
  if (lane == 0) { lsd[w] = s; lsd[4 + w] = s2; lsf[w] = mn; lsf[4 + w] = mx; }
  __syncthreads();
  if (t == 0) {
    rowsum[row]   = (lsd[0] + lsd[1]) + (lsd[2] + lsd[3]);
    rowsumsq[row] = (lsd[4] + lsd[5]) + (lsd[6] + lsd[7]);
    rowmin[row] = (double)fminf(fminf(lsf[0], lsf[1]), fminf(lsf[2], lsf[3]));
    rowmax[row] = (double)fmaxf(fmaxf(lsf[4], lsf[5]), fmaxf(lsf[6], lsf[7]));
  }
}

// ---------------- K1 (fallback path only): per-row stats without split ----------------
__global__ __launch_bounds__(256) void k_rowstats(const float* __restrict__ x,
    double* __restrict__ rowsum, double* __restrict__ rowsumsq,
    double* __restrict__ rowmin, double* __restrict__ rowmax) {
  const int row = blockIdx.x;
  const int t = threadIdx.x;
  const float4* xr = (const float4*)(x + (size_t)row * DCOLS);
  double s = 0.0, s2 = 0.0;
  float mn = 3.4028235e38f, mx = -3.4028235e38f;
  for (int j = t; j < DCOLS / 4; j += 256) {
    float4 v = xr[j];
    double a = v.x, b = v.y, c = v.z, d = v.w;
    s  += (a + b) + (c + d);
    s2 += (a * a + b * b) + (c * c + d * d);
    mn = fminf(mn, fminf(fminf(v.x, v.y), fminf(v.z, v.w)));
    mx = fmaxf(mx, fmaxf(fmaxf(v.x, v.y), fmaxf(v.z, v.w)));
  }
  #pragma unroll
  for (int off = 32; off > 0; off >>= 1) {
    s  += __shfl_down(s, off);
    s2 += __shfl_down(s2, off);
    mn = fminf(mn, __shfl_down(mn, off));
    mx = fmaxf(mx, __shfl_down(mx, off));
  }
  __shared__ double lsd[8];
  __shared__ float  lsf[8];
  const int lane = t & 63, w = t >> 6;
  if (lane == 0) { lsd[w] = s; lsd[4 + w] = s2; lsf[w] = mn; lsf[4 + w] = mx; }
  __syncthreads();
  if (t == 0) {
    rowsum[row]   = (lsd[0] + lsd[1]) + (lsd[2] + lsd[3]);
    rowsumsq[row] = (lsd[4] + lsd[5]) + (lsd[6] + lsd[7]);
    rowmin[row] = (double)fminf(fminf(lsf[0], lsf[1]), fminf(lsf[2], lsf[3]));
    rowmax[row] = (double)fmaxf(fmaxf(lsf[4], lsf[5]), fmaxf(lsf[6], lsf[7]));
  }
}

// ---------------- K2: global scalars (fp64 stats -> float32 np-style scalars) + bc zero ----------------
__global__ __launch_bounds__(256) void k_stats2(
    const double* __restrict__ rowsum, const double* __restrict__ rowsumsq,
    const double* __restrict__ rowmin, const double* __restrict__ rowmax,
    double* __restrict__ m, double* __restrict__ dn, float* __restrict__ fscal,
    float* __restrict__ flg, unsigned* __restrict__ bc) {
#pragma clang fp contract(off)
  const int t = threadIdx.x;
  for (int b = t; b < BINS; b += 256) bc[b] = 0;
  double s = 0.0, s2 = 0.0, mn = 1e300, mx = -1e300;
  for (int r = t; r < NROWS; r += 256) {
    s += rowsum[r]; s2 += rowsumsq[r];
    mn = fmin(mn, rowmin[r]); mx = fmax(mx, rowmax[r]);
  }
  #pragma unroll
  for (int off = 32; off > 0; off >>= 1) {
    s  += __shfl_down(s, off);
    s2 += __shfl_down(s2, off);
    mn = fmin(mn, __shfl_down(mn, off));
    mx = fmax(mx, __shfl_down(mx, off));
  }
  __shared__ double lsd[16];
  const int lane = t & 63, w = t >> 6;
  if (lane == 0) { lsd[w] = s; lsd[4 + w] = s2; lsd[8 + w] = mn; lsd[12 + w] = mx; }
  __syncthreads();
  if (t == 0) {
    double S  = (lsd[0] + lsd[1]) + (lsd[2] + lsd[3]);
    double S2 = (lsd[4] + lsd[5]) + (lsd[6] + lsd[7]);
    double MN = fmin(fmin(lsd[8], lsd[9]), fmin(lsd[10], lsd[11]));
    double MX = fmax(fmax(lsd[12], lsd[13]), fmax(lsd[14], lsd[15]));
    const double N = 16777216.0;
    double mu  = S / N;
    double var = (S2 - S * S / N) / (N - 1.0);
    double sig = sqrt(var);
    float mu32 = (float)mu;
    float sg32 = (float)sig;
    float mnf  = (float)MN;
    float mxf  = (float)MX;
    float lof  = (mnf - mu32) / sg32;
    float hif  = (mxf - mu32) / sg32;
    float wf   = (hif - lof) / 1000.0f;
    fscal[0] = mu32;
    fscal[1] = sg32;
    fscal[2] = lof;
    fscal[3] = wf;
    fscal[4] = 16384.0f * wf;
    fscal[5] = 16777216.0f * wf;
    flg[0] = 0.0f;
  }
  __syncthreads();
  for (int r = t; r < NROWS; r += 256) {
    double rs = rowsum[r];
    m[r]  = rs / 16384.0;
    dn[r] = sqrt(rowsumsq[r] - rs * rs * (1.0 / 16384.0));
  }
}

// ---- K5a: split-K(8) MFMA Gram, 2x2 wave tiling (wave owns 32x32 of the 64x64 tile).
// ---- 1088 blocks = 136 pairs x 8 K-slices (K=2048 each). LDS 32 KB, single-buffer.
__global__ __launch_bounds__(256) void k_gramm_sk(
    const unsigned short* __restrict__ phi, const unsigned short* __restrict__ plo,
    float* __restrict__ Gs) {
  const int pid = blockIdx.x >> 3, ks = blockIdx.x & 7;
  int bi = 0, rem = pid;
  while (rem >= 16 - bi) { rem -= 16 - bi; ++bi; }   // pid -> (bi, bj), bi<=bj
  const int bj = bi + rem;
  const bool diag = (bi == bj);
  __shared__ short As[2][64][64];            // [plane][row][k] bf16, part-swizzled
  __shared__ short Bs[2][64][64];
  const int t = threadIdx.x;
  const int w = t >> 6, l = t & 63;

  // staging roles (unchanged): w0 A-hi, w1 A-lo, w2 B-hi, w3 B-lo; 8 instr x 8 rows.
  const unsigned short* plane = (w & 1) ? plo : phi;
  const int prow0 = (w & 2) ? bj * 64 : bi * 64;
  short* lbase = (w & 2) ? &Bs[w & 1][0][0] : &As[w & 1][0][0];
  const bool skipStage = diag && (w & 2);
  const unsigned short* gbase = plane
      + (size_t)(prow0 + (l >> 3)) * DCOLS + (((l & 7) ^ (l >> 3)) * 8);

  f32x4 acc[2][2] = {{{0.f,0.f,0.f,0.f},{0.f,0.f,0.f,0.f}},
                     {{0.f,0.f,0.f,0.f},{0.f,0.f,0.f,0.f}}};
  double dacc[2][2][4] = {{{0,0,0,0},{0,0,0,0}},{{0,0,0,0},{0,0,0,0}}};

  const int wr = w >> 1, wc = w & 1;          // wave's 32x32 quadrant
  const short* BA0 = diag ? &As[0][0][0] : &Bs[0][0][0];
  const short* BA1 = diag ? &As[1][0][0] : &Bs[1][0][0];
  const int kbeg = ks * 2048;

  for (int k0 = kbeg; k0 < kbeg + 2048; k0 += 64) {
    __syncthreads();                          // previous chunk fully consumed
    if (!skipStage) {
      #pragma unroll
      for (int q = 0; q < 8; ++q)
        GLOAD_LDS16(gbase + (size_t)q * 8 * DCOLS + k0, lbase + q * 512);
    }
    __syncthreads();                          // staging drained
    short8 ah[2][2], al[2][2], bh[2][2], bl[2][2];
    #pragma unroll
    for (int as_ = 0; as_ < 2; ++as_) {
      const int arow = wr * 32 + as_ * 16 + (l & 15);
      const int r7 = arow & 7;
      #pragma unroll
      for (int kk = 0; kk < 2; ++kk) {
        const int p = (kk * 4 + (l >> 4)) ^ r7;
        ah[as_][kk] = *(const short8*)&As[0][arow][p * 8];
        al[as_][kk] = *(const short8*)&As[1][arow][p * 8];
      }
    }
    #pragma unroll
    for (int bs_ = 0; bs_ < 2; ++bs_) {
      const int brow = wc * 32 + bs_ * 16 + (l & 15);
      const int r7 = brow & 7;
      #pragma unroll
      for (int kk = 0; kk < 2; ++kk) {
        const int p = (kk * 4 + (l >> 4)) ^ r7;
        bh[bs_][kk] = *(const short8*)(BA0 + brow * 64 + p * 8);
        bl[bs_][kk] = *(const short8*)(BA1 + brow * 64 + p * 8);
      }
    }
    #pragma unroll
    for (int as_ = 0; as_ < 2; ++as_)
      #pragma unroll
      for (int bs_ = 0; bs_ < 2; ++bs_)
        #pragma unroll
        for (int kk = 0; kk < 2; ++kk) {
          acc[as_][bs_] = __builtin_amdgcn_mfma_f32_16x16x32_bf16(ah[as_][kk], bh[bs_][kk], acc[as_][bs_], 0, 0, 0);
          acc[as_][bs_] = __builtin_amdgcn_mfma_f32_16x16x32_bf16(ah[as_][kk], bl[bs_][kk], acc[as_][bs_], 0, 0, 0);
          acc[as_][bs_] = __builtin_amdgcn_mfma_f32_16x16x32_bf16(al[as_][kk], bh[bs_][kk], acc[as_][bs_], 0, 0, 0);
        }
  }
  #pragma unroll
  for (int as_ = 0; as_ < 2; ++as_)
    #pragma unroll
    for (int bs_ = 0; bs_ < 2; ++bs_)
      #pragma unroll
      for (int v = 0; v < 4; ++v) dacc[as_][bs_][v] = (double)acc[as_][bs_][v];

  // write fp32 slice. C/D layout: col = lane&15, row = (lane>>4)*4 + v  [verified m89/m91]
  float* gt = Gs + ((size_t)pid * KSPL + ks) * 4096;
  #pragma unroll
  for (int as_ = 0; as_ < 2; ++as_)
    #pragma unroll
    for (int bs_ = 0; bs_ < 2; ++bs_)
      #pragma unroll
      for (int v = 0; v < 4; ++v)
        gt[(wr * 32 + as_ * 16 + (l >> 4) * 4 + v) * 64 + wc * 32 + bs_ * 16 + (l & 15)]
            = (float)dacc[as_][bs_][v];
}

// ---- K5e: merged per-pair epilogue (blocks 0..NPAIR-1 when doGepi) + spot-check partials ----
// gepi: sum KSPL slices (fp64, fixed order), cov, both-direction |corr| partials.
// check (last 96 blocks): 12 entries x 8 col-groups of fp64-exact fpart reference.
__global__ __launch_bounds__(256) void k_gepi_chk(const float* __restrict__ x,
    const float* __restrict__ Gs, const double* __restrict__ m,
    const double* __restrict__ dn, double* __restrict__ fpart,
    double* __restrict__ chkpart, int nGepi) {
  const int t = threadIdx.x;
  if ((int)blockIdx.x >= nGepi) {
    // ---- spot-check partial ----
    const int b = blockIdx.x - nGepi;
    const int e = b >> 3, grp = b & 7;
    const int cl = t >> 5;            // 0..7: col within group
    const int ksg = t & 31;           // 0..31: k segment (512 elems)
    const int trow = CHK_TR[e];
    const int col  = CHK_CB[e] + grp * 8 + cl;
    const float4* xa = (const float4*)(x + (size_t)trow * DCOLS) + ksg * 128;
    const float4* xb = (const float4*)(x + (size_t)col  * DCOLS) + ksg * 128;
    double g = 0.0;
    for (int k = 0; k < 128; ++k) {
      float4 va = xa[k], vb = xb[k];
      g += (double)va.x * vb.x + (double)va.y * vb.y
         + (double)va.z * vb.z + (double)va.w * vb.w;
    }
    g += __shfl_xor(g, 1); g += __shfl_xor(g, 2); g += __shfl_xor(g, 4);
    g += __shfl_xor(g, 8); g += __shfl_xor(g, 16);
    __shared__ double cd[8];
    if (ksg == 0) cd[cl] = g;
    __syncthreads();
    if (t == 0) {
      double s = 0.0;
      #pragma unroll
      for (int i = 0; i < 8; ++i) {
        int c = CHK_CB[e] + grp * 8 + i;
        double cov = cd[i] - 16384.0 * m[trow] * m[c];
        s += fabs(cov) / dn[c];
      }
      chkpart[e * 8 + grp] = s;
    }
    return;
  }
  // ---- gepi ----
  const int pid = blockIdx.x;
  int bi = 0, rem = pid;
  while (rem >= 16 - bi) { rem -= 16 - bi; ++bi; }
  const int bj = bi + rem;
  const bool diag = (bi == bj);
  __shared__ double Gt[64][65];               // +1 pad: kills bank conflict
  const float* g = Gs + (size_t)pid * KSPL * 4096;
  for (int i = t; i < 4096; i += 256) {
    double sg = (((double)g[i]           + (double)g[4096 + i])
              +  ((double)g[8192 + i]    + (double)g[12288 + i]))
              + (((double)g[16384 + i]   + (double)g[20480 + i])
              +  ((double)g[24576 + i]   + (double)g[28672 + i]));  // fixed order
    Gt[i >> 6][i & 63] = sg;
  }
  __syncthreads();
  // row-direction: thread t -> row r=t>>2, col quarter q=t&3 (16 cols)
  {
    const int r = t >> 2, q = t & 3;
    const double mi = m[bi * 64 + r] * 16384.0;
    double s = 0.0;
    #pragma unroll
    for (int i = 0; i < 16; ++i) {
      const int c = q * 16 + i;
      double cov = Gt[r][c] - mi * m[bj * 64 + c];
      s += fabs(cov) / dn[bj * 64 + c];
    }
    s += __shfl_xor(s, 1); s += __shfl_xor(s, 2);
    if (q == 0) fpart[(size_t)(bi * 64 + r) * 16 + bj] = s;
  }
  // col-direction (off-diag): thread t -> col c=t>>2, row quarter q=t&3
  if (!diag) {
    const int c = t >> 2, q = t & 3;
    const double mj = m[bj * 64 + c] * 16384.0;
    double sc = 0.0;
    #pragma unroll
    for (int i = 0; i < 16; ++i) {
      const int r = q * 16 + i;
      double cov = Gt[r][c] - m[bi * 64 + r] * mj;
      sc += fabs(cov) / dn[bi * 64 + r];
    }
    sc += __shfl_xor(sc, 1); sc += __shfl_xor(sc, 2);
    if (q == 0) fpart[(size_t)(bj * 64 + c) * 16 + bi] = sc;
  }
}

// ---------------- K5b: fallback fp32-VALU Gram (small ws) ----------------
__global__ __launch_bounds__(256) void k_gram(const float* __restrict__ x,
    const double* __restrict__ m, const double* __restrict__ dn,
    double* __restrict__ fpart) {
  __shared__ float As[32][72];
  __shared__ float Bs[32][72];
  __shared__ double red[64][16];
  const int t = threadIdx.x;
  const int bi = blockIdx.y, bj = blockIdx.x;
  const int tx = t & 15, ty = t >> 4;
  const int lr = t >> 2, lc = t & 3;
  const float* Ap = x + (size_t)(bi * 64 + lr) * DCOLS;
  const float* Bp = x + (size_t)(bj * 64 + lr) * DCOLS;
  double acc[4][4];
  #pragma unroll
  for (int i = 0; i < 4; ++i)
    #pragma unroll
    for (int j = 0; j < 4; ++j) acc[i][j] = 0.0;
  float4 a0 = ((const float4*)Ap)[lc];
  float4 a1 = ((const float4*)Ap)[lc + 4];
  float4 b0 = ((const float4*)Bp)[lc];
  float4 b1 = ((const float4*)Bp)[lc + 4];
  for (int k0 = 0; k0 < DCOLS; k0 += 32) {
    __syncthreads();
    {
      const float* a0p = (const float*)&a0;
      const float* a1p = (const float*)&a1;
      const float* b0p = (const float*)&b0;
      const float* b1p = (const float*)&b1;
      #pragma unroll
      for (int jj = 0; jj < 4; ++jj) {
        As[lc * 4 + jj][lr]      = a0p[jj];
        As[16 + lc * 4 + jj][lr] = a1p[jj];
        Bs[lc * 4 + jj][lr]      = b0p[jj];
        Bs[16 + lc * 4 + jj][lr] = b1p[jj];
      }
    }
    __syncthreads();
    if (k0 + 32 < DCOLS) {
      a0 = ((const float4*)(Ap + k0 + 32))[lc];
      a1 = ((const float4*)(Ap + k0 + 32))[lc + 4];
      b0 = ((const float4*)(Bp + k0 + 32))[lc];
      b1 = ((const float4*)(Bp + k0 + 32))[lc + 4];
    }
    float ac[4][4];
    #pragma unroll
    for (int i = 0; i < 4; ++i)
      #pragma unroll
      for (int j = 0; j < 4; ++j) ac[i][j] = 0.0f;
    #pragma unroll
    for (int k = 0; k < 32; ++k) {
      const float4 av = *(const float4*)&As[k][ty * 4];
      const float4 bv = *(const float4*)&Bs[k][tx * 4];
      const float aa[4] = {av.x, av.y, av.z, av.w};
      const float bb[4] = {bv.x, bv.y, bv.z, bv.w};
      #pragma unroll
      for (int i = 0; i < 4; ++i)
        #pragma unroll
        for (int j = 0; j < 4; ++j)
          ac[i][j] += aa[i] * bb[j];
    }
    #pragma unroll
    for (int i = 0; i < 4; ++i)
      #pragma unroll
      for (int j = 0; j < 4; ++j) acc[i][j] += (double)ac[i][j];
  }
  double mr[4], mc[4], dc[4];
  #pragma unroll
  for (int i = 0; i < 4; ++i) mr[i] = m[bi * 64 + ty * 4 + i];
  #pragma unroll
  for (int j = 0; j < 4; ++j) {
    int col = bj * 64 + tx * 4 + j;
    mc[j] = m[col]; dc[j] = dn[col];
  }
  #pragma unroll
  for (int i = 0; i < 4; ++i) {
    double pi = 0.0;
    #pragma unroll
    for (int j = 0; j < 4; ++j) {
      double cov = acc[i][j] - 16384.0 * mr[i] * mc[j];
      pi += fabs(cov) / dc[j];
    }
    red[ty * 4 + i][tx] = pi;
  }
  __syncthreads();
  if (t < 64) {
    double ssum = 0.0;
    #pragma unroll
    for (int q = 0; q < 16; ++q) ssum += red[t][q];
    fpart[(size_t)(bi * 64 + t) * 16 + bj] = ssum;
  }
}

// ---------------- K3: per-row histogram (float32 np binning) + local entropy ----------------
__global__ __launch_bounds__(256) void k_hist(const float* __restrict__ x,
    const float* __restrict__ fscal, double* __restrict__ localent,
    unsigned* __restrict__ bc) {
#pragma clang fp contract(off)
  __shared__ unsigned h[BINS];
  const int row = blockIdx.x, t = threadIdx.x;
  for (int b = t; b < BINS; b += 256) h[b] = 0;
  __syncthreads();
  const float mu32 = fscal[0], sg32 = fscal[1], lof = fscal[2], wf = fscal[3];
  const float4* xr = (const float4*)(x + (size_t)row * DCOLS);
  for (int j = t; j < DCOLS / 4; j += 256) {
    float4 v = xr[j];
    float vv[4] = {v.x, v.y, v.z, v.w};
    #pragma unroll
    for (int c = 0; c < 4; ++c) {
      float tn = (vv[c] - mu32) / sg32;
      float q  = (tn - lof) / wf;
      int idx = (int)floorf(q);
      idx = idx < 0 ? 0 : (idx > BINS - 1 ? BINS - 1 : idx);
      atomicAdd(&h[idx], 1u);
    }
  }
  __syncthreads();
  const double Dw = (double)fscal[4];
  double ls = 0.0;
  for (int b = t; b < BINS; b += 256) {
    unsigned c = h[b];
    if (c) {
      atomicAdd(&bc[b], c);
      double pd = (double)c / Dw;
      ls -= pd * log2(pd);
    }
  }
  #pragma unroll
  for (int off = 32; off > 0; off >>= 1) ls += __shfl_down(ls, off);
  __shared__ double lsd[4];
  const int lane = t & 63, w = t >> 6;
  if (lane == 0) lsd[w] = ls;
  __syncthreads();
  if (t == 0) localent[row] = (lsd[0] + lsd[1]) + (lsd[2] + lsd[3]);
}

// ---------------- K4: batch entropy + per-row pf/keepf + fpart spot-check compare ----------------
__global__ __launch_bounds__(256) void k_final(const unsigned* __restrict__ bc,
    const float* __restrict__ fscal, const double* __restrict__ localent,
    const double* __restrict__ fpart, const double* __restrict__ dn,
    const double* __restrict__ chkpart, float* __restrict__ flg,
    float* __restrict__ pf, float* __restrict__ kf) {
#pragma clang fp contract(off)
  const int t = threadIdx.x;
  if (t < 12) {    // compare spot-check entries vs fpart (flg consumed by k_apply)
    double s = 0.0;
    #pragma unroll
    for (int q = 0; q < 8; ++q) s += chkpart[t * 8 + q];
    double got = fpart[(size_t)CHK_TR[t] * 16 + CHK_SL[t]];
    if (fabs(got - s) > 2e-3 * fmax(fabs(s), 1e-30))
      atomicAdd(flg, 1e6f * (float)(t + 1));
  }
  const double Nw = (double)fscal[5];
  double be = 0.0;
  for (int b = t; b < BINS; b += 256) {
    unsigned c = bc[b];
    if (c) { double pd = (double)c / Nw; be -= pd * log2(pd); }
  }
  #pragma unroll
  for (int off = 32; off > 0; off >>= 1) be += __shfl_down(be, off);
  __shared__ double lsd[4];
  __shared__ double sbent;
  const int lane = t & 63, w = t >> 6;
  if (lane == 0) lsd[w] = be;
  __syncthreads();
  if (t == 0) sbent = (lsd[0] + lsd[1]) + (lsd[2] + lsd[3]);
  __syncthreads();
  const float bef = (float)sbent;
  for (int r = t; r < NROWS; r += 256) {
    double s = 0.0;
    #pragma unroll
    for (int q = 0; q < 16; ++q) s += fpart[(size_t)r * 16 + q];
    float f1f = (float)(s / (dn[r] * 1024.0));
    float lef = (float)localent[r];
    float f2f = lef / bef;
    if (f2f == 0.0f) { f1f = 0.0f; f2f = 1.0f; }
    else if (f2f < 1.0f) f2f = 1.0f / f2f;
    float keepf = f1f / f2f;
    pf[r] = 1.0f - keepf;
    kf[r] = keepf;
  }
}

// ---------------- K6: elementwise masked scale (float32 compare + division) ----------------
__global__ __launch_bounds__(256) void k_apply(const float* __restrict__ x,
    const float* __restrict__ u, const float* __restrict__ pf,
    const float* __restrict__ kf, const float* __restrict__ flg,
    float* __restrict__ out) {
#pragma clang fp contract(off)
  const size_t e = ((size_t)blockIdx.x * 256 + threadIdx.x) * 4;
  const float fl = flg[0];
  if (fl != 0.0f) {           // diagnostic mode: encode check code in out[0]
    float4 o = {0.f, 0.f, 0.f, 0.f};
    if (e == 0) o.x = fl;
    *(float4*)(out + e) = o;
    return;
  }
  const int row = (int)(e >> 14);
  const float pr = pf[row], kr = kf[row];
  const float4 xv = *(const float4*)(x + e);
  const float4 uv = *(const float4*)(u + e);
  float4 o;
  o.x = (uv.x > pr) ? (xv.x / kr) : 0.0f;
  o.y = (uv.y > pr) ? (xv.y / kr) : 0.0f;
  o.z = (uv.z > pr) ? (xv.z / kr) : 0.0f;
  o.w = (uv.w > pr) ? (xv.w / kr) : 0.0f;
  *(float4*)(out + e) = o;
}

extern "C" void kernel_launch(void* const* d_in, const int* in_sizes, int n_in,
                              void* d_out, int out_size, void* d_ws, size_t ws_size,
                              hipStream_t stream) {
  const float* x = (const float*)d_in[0];
  const float* u = (const float*)d_in[1];
  float* out = (float*)d_out;

  const size_t PLANE = (size_t)NROWS * DCOLS * sizeof(unsigned short);  // 32 MB
  const size_t NDBL  = 7 * 1024 + (size_t)NROWS * 16 + 96;              // stats + fpart + chkpart
  const size_t TAILB = NDBL * 8 + (2056 + 4) * 4 + BINS * 4;
  const bool big = ws_size >= 2 * PLANE + TAILB;

  char* base = (char*)d_ws;
  unsigned short* phi = (unsigned short*)base;
  unsigned short* plo = (unsigned short*)(base + PLANE);
  double* W = big ? (double*)(base + 2 * PLANE) : (double*)base;

  double* rowsum   = W;
  double* rowsumsq = W + 1024;
  double* rowmin   = W + 2048;
  double* rowmax   = W + 3072;
  double* m        = W + 4096;
  double* dn       = W + 5120;
  double* localent = W + 6144;
  double* fpart    = W + 7168;                        // 1024*16 doubles
  double* chkpart  = W + 7168 + (size_t)NROWS * 16;   // 96 doubles
  float*  F        = (float*)(chkpart + 96);
  float*  pf       = F;
  float*  kf       = F + 1024;
  float*  fscal    = F + 2048;          // 8 floats
  float*  flg      = F + 2056;          // 4 floats
  unsigned* bc     = (unsigned*)(F + 2060);

  if (big) {
    float* Gs = out;   // scratch: 136*8*4096 = 4.46M floats of the 16.7M out buffer
    k_rowsplit<<<NROWS, 256, 0, stream>>>(x, phi, plo, rowsum, rowsumsq, rowmin, rowmax);
    k_stats2<<<1, 256, 0, stream>>>(rowsum, rowsumsq, rowmin, rowmax, m, dn, fscal, flg, bc);
    k_gramm_sk<<<NPAIR * KSPL, 256, 0, stream>>>(phi, plo, Gs);
    k_gepi_chk<<<NPAIR + 96, 256, 0, stream>>>(x, Gs, m, dn, fpart, chkpart, NPAIR);
  } else {
    k_rowstats<<<NROWS, 256, 0, stream>>>(x, rowsum, rowsumsq, rowmin, rowmax);
    k_stats2<<<1, 256, 0, stream>>>(rowsum, rowsumsq, rowmin, rowmax, m, dn, fscal, flg, bc);
    k_gram<<<dim3(16, 16), 256, 0, stream>>>(x, m, dn, fpart);
    k_gepi_chk<<<96, 256, 0, stream>>>(x, (const float*)out, m, dn, fpart, chkpart, 0);
  }
  k_hist<<<NROWS, 256, 0, stream>>>(x, fscal, localent, bc);
  k_final<<<1, 256, 0, stream>>>(bc, fscal, localent, fpart, dn, chkpart, flg, pf, kf);
  k_apply<<<NTOT / (256 * 4), 256, 0, stream>>>(x, u, pf, kf, flg, out);
}